// Round 4
// baseline (5953.527 us; speedup 1.0000x reference)
//
#include <hip/hip_runtime.h>

#define BLK 256

__device__ __forceinline__ unsigned short f2bf(float f) {
    unsigned int u = __float_as_uint(f);
    u += 0x7FFFu + ((u >> 16) & 1u);
    return (unsigned short)(u >> 16);
}
__device__ __forceinline__ float bf2f(unsigned short s) {
    return __uint_as_float(((unsigned int)s) << 16);
}

// out[M, half*64 : half*64+64] = (relu?)(in[M,K] @ W[K,128] + bias)[cols]
// W column-half (K x 64, <=32KB) + bias staged in LDS; grid-stride over
// 16-row input tiles staged in LDS; thread owns (row, 4 cols).
template <int OUT_BF16>
__global__ __launch_bounds__(BLK) void gemm_rm(
    const float* __restrict__ in, const float* __restrict__ W,
    const float* __restrict__ bias, void* __restrict__ outv,
    int M, int K, int do_relu)
{
    __shared__ float Wl[128 * 64];
    __shared__ float inl[16 * 128];
    __shared__ float bl[64];
    const int tid = threadIdx.x;
    const int half = blockIdx.y;

    for (int idx = tid; idx < K * 64; idx += BLK) {
        int k = idx >> 6, j = idx & 63;
        Wl[idx] = W[k * 128 + half * 64 + j];
    }
    if (tid < 64) bl[tid] = bias[half * 64 + tid];
    __syncthreads();

    const int r  = tid >> 4;          // 0..15 row within tile
    const int j4 = (tid & 15) << 2;   // 0,4,..,60 col within half
    const int ntiles = M >> 4;        // M divisible by 16 for all our M
    const int n4 = (16 * K) >> 2;

    for (int tile = blockIdx.x; tile < ntiles; tile += gridDim.x) {
        const size_t row0 = (size_t)tile << 4;
        const float4* s4 = (const float4*)(in + row0 * K);
        float4* d4 = (float4*)inl;
        for (int idx = tid; idx < n4; idx += BLK) d4[idx] = s4[idx];
        __syncthreads();

        float4 acc = make_float4(bl[j4], bl[j4 + 1], bl[j4 + 2], bl[j4 + 3]);
        const float* a = &inl[r * K];
        #pragma unroll 4
        for (int k = 0; k < K; k += 4) {
            const float4 a4 = *(const float4*)(a + k);
            float4 w;
            w = *(const float4*)(&Wl[(k + 0) * 64 + j4]);
            acc.x += a4.x * w.x; acc.y += a4.x * w.y; acc.z += a4.x * w.z; acc.w += a4.x * w.w;
            w = *(const float4*)(&Wl[(k + 1) * 64 + j4]);
            acc.x += a4.y * w.x; acc.y += a4.y * w.y; acc.z += a4.y * w.z; acc.w += a4.y * w.w;
            w = *(const float4*)(&Wl[(k + 2) * 64 + j4]);
            acc.x += a4.z * w.x; acc.y += a4.z * w.y; acc.z += a4.z * w.z; acc.w += a4.z * w.w;
            w = *(const float4*)(&Wl[(k + 3) * 64 + j4]);
            acc.x += a4.w * w.x; acc.y += a4.w * w.y; acc.z += a4.w * w.z; acc.w += a4.w * w.w;
        }
        if (do_relu) {
            acc.x = fmaxf(acc.x, 0.f); acc.y = fmaxf(acc.y, 0.f);
            acc.z = fmaxf(acc.z, 0.f); acc.w = fmaxf(acc.w, 0.f);
        }
        const size_t o = (row0 + r) * 128 + half * 64 + j4;
        if (OUT_BF16) {
            ushort4 ob;
            ob.x = f2bf(acc.x); ob.y = f2bf(acc.y);
            ob.z = f2bf(acc.z); ob.w = f2bf(acc.w);
            *(ushort4*)((unsigned short*)outv + o) = ob;
        } else {
            *(float4*)((float*)outv + o) = acc;
        }
        __syncthreads();
    }
}

// z = h (vectorized copy), so scatter accumulates into h + agg
__global__ __launch_bounds__(BLK) void copy_f4(
    const float4* __restrict__ src, float4* __restrict__ dstp, int n4)
{
    int i = blockIdx.x * BLK + threadIdx.x;
    if (i < n4) dstp[i] = src[i];
}

// For each edge: m = relu(h[src] + e), atomicAdd into z[dst].
// One thread per (edge, 4-col group). E_BF16 selects e storage dtype.
template <int E_BF16>
__global__ __launch_bounds__(BLK) void scatter_msg(
    const float* __restrict__ h, const void* __restrict__ ev_,
    const int* __restrict__ src, const int* __restrict__ dst,
    float* __restrict__ z, int nE)
{
    long long item = (long long)blockIdx.x * BLK + threadIdx.x;
    if (item >= (long long)nE * 32) return;
    int edge = (int)(item >> 5);
    int c4 = ((int)item & 31) << 2;
    int s = src[edge], d = dst[edge];
    const float4 hv = *(const float4*)(h + (size_t)s * 128 + c4);
    float ex, ey, ezv, ew;
    if (E_BF16) {
        const ushort4 ev = *(const ushort4*)((const unsigned short*)ev_ + (size_t)edge * 128 + c4);
        ex = bf2f(ev.x); ey = bf2f(ev.y); ezv = bf2f(ev.z); ew = bf2f(ev.w);
    } else {
        const float4 ev = *(const float4*)((const float*)ev_ + (size_t)edge * 128 + c4);
        ex = ev.x; ey = ev.y; ezv = ev.z; ew = ev.w;
    }
    float* zp = z + (size_t)d * 128 + c4;
    atomicAdd(zp + 0, fmaxf(hv.x + ex, 0.f));
    atomicAdd(zp + 1, fmaxf(hv.y + ey, 0.f));
    atomicAdd(zp + 2, fmaxf(hv.z + ezv, 0.f));
    atomicAdd(zp + 3, fmaxf(hv.w + ew, 0.f));
}

extern "C" void kernel_launch(void* const* d_in, const int* in_sizes, int n_in,
                              void* d_out, int out_size, void* d_ws, size_t ws_size,
                              hipStream_t stream) {
    const float* nf  = (const float*)d_in[0];
    const float* ef  = (const float*)d_in[1];
    const int*   src = (const int*)d_in[2];
    const int*   dst = (const int*)d_in[3];
    const float* Wn  = (const float*)d_in[4];
    const float* bn  = (const float*)d_in[5];
    const float* We1 = (const float*)d_in[6];
    const float* be1 = (const float*)d_in[7];
    const float* We2 = (const float*)d_in[8];
    const float* be2 = (const float*)d_in[9];
    const float* W1  = (const float*)d_in[10];
    const float* b1  = (const float*)d_in[11];
    const float* W2  = (const float*)d_in[12];
    const float* b2  = (const float*)d_in[13];

    const int N_ = 100000, E_ = 600000, L_ = 4;

    // workspace layouts:
    //  f32-e: e f32 [E,128] 307.2MB | z 51.2MB | hidN 51.2MB   = 409.6MB
    //  bf16-e: e bf16 [E,128] 153.6MB | z 51.2MB | hidN 51.2MB = 256.0MB
    //  (hidE f32 [E/4,128] 76.8MB aliases z..z+102.4MB during edge phase)
    const size_t nodeBytes = (size_t)N_ * 128 * 4;
    const size_t needF = (size_t)E_ * 128 * 4 + 2 * nodeBytes;
    const size_t needB = (size_t)E_ * 128 * 2 + 2 * nodeBytes;
    const int eF32 = (ws_size >= needF) ? 1 : 0;
    if (!eF32 && ws_size < needB) return;  // clean diagnostic fail

    float* h = (float*)d_out;
    char*  ws = (char*)d_ws;
    void*  e  = (void*)ws;
    const size_t eBytes = eF32 ? (size_t)E_ * 128 * 4 : (size_t)E_ * 128 * 2;
    float* z    = (float*)(ws + eBytes);
    float* hidN = z + (size_t)N_ * 128;
    float* hidE = z;

    dim3 blk(BLK);
    dim3 gN(2048, 2);

    // 1) h = relu(nf @ Wn + bn)
    gemm_rm<0><<<gN, blk, 0, stream>>>(nf, Wn, bn, h, N_, 64, 1);

    // 2) e = relu(ef @ We1 + be1) @ We2 + be2, in 4 row-chunks
    const int Mc = E_ / 4;  // 150000
    for (int c = 0; c < 4; ++c) {
        const float* efc = ef + (size_t)c * Mc * 16;
        gemm_rm<0><<<gN, blk, 0, stream>>>(efc, We1, be1, hidE, Mc, 16, 1);
        if (eF32) {
            float* ec = (float*)e + (size_t)c * Mc * 128;
            gemm_rm<0><<<gN, blk, 0, stream>>>(hidE, We2, be2, ec, Mc, 128, 0);
        } else {
            unsigned short* ec = (unsigned short*)e + (size_t)c * Mc * 128;
            gemm_rm<1><<<gN, blk, 0, stream>>>(hidE, We2, be2, ec, Mc, 128, 0);
        }
    }

    // 3) L layers of GINE
    const int n4 = N_ * 128 / 4;
    const int ncp = (n4 + BLK - 1) / BLK;
    const int nsc = (int)(((long long)E_ * 32 + BLK - 1) / BLK);
    for (int l = 0; l < L_; ++l) {
        copy_f4<<<ncp, blk, 0, stream>>>((const float4*)h, (float4*)z, n4);
        if (eF32)
            scatter_msg<0><<<nsc, blk, 0, stream>>>(h, e, src, dst, z, E_);
        else
            scatter_msg<1><<<nsc, blk, 0, stream>>>(h, e, src, dst, z, E_);
        gemm_rm<0><<<gN, blk, 0, stream>>>(z, W1 + (size_t)l * 128 * 128,
                                           b1 + (size_t)l * 128, hidN, N_, 128, 1);
        gemm_rm<0><<<gN, blk, 0, stream>>>(hidN, W2 + (size_t)l * 128 * 128,
                                           b2 + (size_t)l * 128, h, N_, 128, 1);
    }
}

// Round 5
// 2253.515 us; speedup vs baseline: 2.6419x; 2.6419x over previous
//
#include <hip/hip_runtime.h>

#define BLK 256

__device__ __forceinline__ unsigned short f2bf(float f) {
    unsigned int u = __float_as_uint(f);
    u += 0x7FFFu + ((u >> 16) & 1u);
    return (unsigned short)(u >> 16);
}
__device__ __forceinline__ float bf2f(unsigned short s) {
    return __uint_as_float(((unsigned int)s) << 16);
}

// out[M, half*64 : half*64+64] = (relu?)(in[M,K] @ W[K,128] + bias)[cols]
// W column-half (K x 64, <=32KB) + bias staged in LDS; grid-stride over
// 16-row input tiles staged in LDS; thread owns (row, 4 cols).
template <int IN_BF16, int OUT_BF16>
__global__ __launch_bounds__(BLK) void gemm_rm(
    const void* __restrict__ inv, const float* __restrict__ W,
    const float* __restrict__ bias, void* __restrict__ outv,
    int M, int K, int do_relu)
{
    __shared__ float Wl[128 * 64];
    __shared__ float inl[16 * 128];
    __shared__ float bl[64];
    const int tid = threadIdx.x;
    const int half = blockIdx.y;

    for (int idx = tid; idx < K * 64; idx += BLK) {
        int k = idx >> 6, j = idx & 63;
        Wl[idx] = W[k * 128 + half * 64 + j];
    }
    if (tid < 64) bl[tid] = bias[half * 64 + tid];
    __syncthreads();

    const int r  = tid >> 4;          // 0..15 row within tile
    const int j4 = (tid & 15) << 2;   // 0,4,..,60 col within half
    const int ntiles = M >> 4;        // M divisible by 16 for all our M
    const int n4 = (16 * K) >> 2;     // 4-element groups per tile

    for (int tile = blockIdx.x; tile < ntiles; tile += gridDim.x) {
        const size_t row0 = (size_t)tile << 4;
        if (IN_BF16) {
            const ushort4* s4 = (const ushort4*)((const unsigned short*)inv + row0 * K);
            float4* d4 = (float4*)inl;
            for (int idx = tid; idx < n4; idx += BLK) {
                ushort4 u = s4[idx];
                d4[idx] = make_float4(bf2f(u.x), bf2f(u.y), bf2f(u.z), bf2f(u.w));
            }
        } else {
            const float4* s4 = (const float4*)((const float*)inv + row0 * K);
            float4* d4 = (float4*)inl;
            for (int idx = tid; idx < n4; idx += BLK) d4[idx] = s4[idx];
        }
        __syncthreads();

        float4 acc = make_float4(bl[j4], bl[j4 + 1], bl[j4 + 2], bl[j4 + 3]);
        const float* a = &inl[r * K];
        #pragma unroll 4
        for (int k = 0; k < K; k += 4) {
            const float4 a4 = *(const float4*)(a + k);
            float4 w;
            w = *(const float4*)(&Wl[(k + 0) * 64 + j4]);
            acc.x += a4.x * w.x; acc.y += a4.x * w.y; acc.z += a4.x * w.z; acc.w += a4.x * w.w;
            w = *(const float4*)(&Wl[(k + 1) * 64 + j4]);
            acc.x += a4.y * w.x; acc.y += a4.y * w.y; acc.z += a4.y * w.z; acc.w += a4.y * w.w;
            w = *(const float4*)(&Wl[(k + 2) * 64 + j4]);
            acc.x += a4.z * w.x; acc.y += a4.z * w.y; acc.z += a4.z * w.z; acc.w += a4.z * w.w;
            w = *(const float4*)(&Wl[(k + 3) * 64 + j4]);
            acc.x += a4.w * w.x; acc.y += a4.w * w.y; acc.z += a4.w * w.z; acc.w += a4.w * w.w;
        }
        if (do_relu) {
            acc.x = fmaxf(acc.x, 0.f); acc.y = fmaxf(acc.y, 0.f);
            acc.z = fmaxf(acc.z, 0.f); acc.w = fmaxf(acc.w, 0.f);
        }
        const size_t o = (row0 + r) * 128 + half * 64 + j4;
        if (OUT_BF16) {
            ushort4 ob;
            ob.x = f2bf(acc.x); ob.y = f2bf(acc.y);
            ob.z = f2bf(acc.z); ob.w = f2bf(acc.w);
            *(ushort4*)((unsigned short*)outv + o) = ob;
        } else {
            *(float4*)((float*)outv + o) = acc;
        }
        __syncthreads();
    }
}

// ---- CSR build (dst is layer-invariant: build once, use 4x) ----

__global__ __launch_bounds__(BLK) void hist_k(
    const int* __restrict__ dst, int* __restrict__ counts, int nE)
{
    int i = blockIdx.x * BLK + threadIdx.x;
    if (i < nE) atomicAdd(&counts[dst[i]], 1);
}

// per-block (1024-elem chunk) sums
__global__ __launch_bounds__(BLK) void scan1_k(
    const int* __restrict__ counts, int* __restrict__ blockSums, int n)
{
    __shared__ int s[BLK];
    const int t = threadIdx.x, b = blockIdx.x;
    const int base = b * 1024 + t * 4;
    int sum = 0;
    #pragma unroll
    for (int j = 0; j < 4; ++j) { int i = base + j; if (i < n) sum += counts[i]; }
    s[t] = sum; __syncthreads();
    for (int off = 128; off > 0; off >>= 1) {
        if (t < off) s[t] += s[t + off];
        __syncthreads();
    }
    if (t == 0) blockSums[b] = s[0];
}

// serial exclusive scan of block sums (nb ~ 98), writes offsets[n] = total
__global__ void scan2_k(int* __restrict__ blockSums, int nb,
                        int* __restrict__ offsets, int n)
{
    if (threadIdx.x == 0 && blockIdx.x == 0) {
        int run = 0;
        for (int i = 0; i < nb; ++i) { int v = blockSums[i]; blockSums[i] = run; run += v; }
        offsets[n] = run;
    }
}

// intra-chunk exclusive scan + block offset -> offsets[]
__global__ __launch_bounds__(BLK) void scan3_k(
    const int* __restrict__ counts, const int* __restrict__ blockSums,
    int* __restrict__ offsets, int n)
{
    __shared__ int s[BLK];
    const int t = threadIdx.x, b = blockIdx.x;
    const int base = b * 1024 + t * 4;
    int c[4]; int tsum = 0;
    #pragma unroll
    for (int j = 0; j < 4; ++j) {
        c[j] = (base + j < n) ? counts[base + j] : 0;
        tsum += c[j];
    }
    s[t] = tsum; __syncthreads();
    for (int off = 1; off < BLK; off <<= 1) {
        int v = (t >= off) ? s[t - off] : 0;
        __syncthreads();
        s[t] += v;
        __syncthreads();
    }
    int run = s[t] - tsum + blockSums[b];
    #pragma unroll
    for (int j = 0; j < 4; ++j) {
        if (base + j < n) { offsets[base + j] = run; run += c[j]; }
    }
}

__global__ __launch_bounds__(BLK) void fill_k(
    const int* __restrict__ dst, const int* __restrict__ offsets,
    int* __restrict__ cursor, int* __restrict__ eidx, int nE)
{
    int i = blockIdx.x * BLK + threadIdx.x;
    if (i < nE) {
        int d = dst[i];
        int pos = offsets[d] + atomicAdd(&cursor[d], 1);
        eidx[pos] = i;
    }
}

// ---- fused aggregation: z[n] = h[n] + sum_{e in CSR[n]} relu(h[src[e]] + e) ----
// 32 lanes per node (8 nodes per block), register accumulation, no atomics.
__global__ __launch_bounds__(BLK) void agg_k(
    const float* __restrict__ h, const unsigned short* __restrict__ e,
    const int* __restrict__ srcv, const int* __restrict__ eidx,
    const int* __restrict__ offsets, float* __restrict__ z, int nN)
{
    const int t = threadIdx.x;
    const int node = blockIdx.x * 8 + (t >> 5);
    if (node >= nN) return;
    const int c4 = (t & 31) << 2;
    float4 acc = *(const float4*)(h + (size_t)node * 128 + c4);  // (1+eps)*h, eps=0
    const int beg = offsets[node], end = offsets[node + 1];
    for (int i = beg; i < end; ++i) {
        const int eg = eidx[i];
        const int s = srcv[eg];
        const float4 hv = *(const float4*)(h + (size_t)s * 128 + c4);
        const ushort4 ev = *(const ushort4*)(e + (size_t)eg * 128 + c4);
        acc.x += fmaxf(hv.x + bf2f(ev.x), 0.f);
        acc.y += fmaxf(hv.y + bf2f(ev.y), 0.f);
        acc.z += fmaxf(hv.z + bf2f(ev.z), 0.f);
        acc.w += fmaxf(hv.w + bf2f(ev.w), 0.f);
    }
    *(float4*)(z + (size_t)node * 128 + c4) = acc;
}

extern "C" void kernel_launch(void* const* d_in, const int* in_sizes, int n_in,
                              void* d_out, int out_size, void* d_ws, size_t ws_size,
                              hipStream_t stream) {
    const float* nf  = (const float*)d_in[0];
    const float* ef  = (const float*)d_in[1];
    const int*   src = (const int*)d_in[2];
    const int*   dst = (const int*)d_in[3];
    const float* Wn  = (const float*)d_in[4];
    const float* bn  = (const float*)d_in[5];
    const float* We1 = (const float*)d_in[6];
    const float* be1 = (const float*)d_in[7];
    const float* We2 = (const float*)d_in[8];
    const float* be2 = (const float*)d_in[9];
    const float* W1  = (const float*)d_in[10];
    const float* b1  = (const float*)d_in[11];
    const float* W2  = (const float*)d_in[12];
    const float* b2  = (const float*)d_in[13];

    const int N_ = 100000, E_ = 600000, L_ = 4;

    // workspace layout (233.6 MB total; known-safe budget is 256.0 MB):
    //   e    bf16 [E,128]              : 153.6 MB  @ 0
    //   z    f32  [N,128]              :  51.2 MB  @ 153.6 MB
    //   hidN bf16 [N,128]              :  25.6 MB  @ 204.8 MB
    //   (hidE f32 [E/4,128] = 76.8 MB aliases z+hidN during edge phase)
    //   CSR  eidx int[E] 2.4 MB | counts int[N] 0.4 MB |
    //        offsets int[N+1] | blockSums        @ 230.4 MB
    const size_t eB  = (size_t)E_ * 128 * 2;   // 153,600,000
    const size_t zB  = (size_t)N_ * 128 * 4;   //  51,200,000
    const size_t hnB = (size_t)N_ * 128 * 2;   //  25,600,000
    const size_t csrOff = eB + zB + hnB;       // 230,400,000
    const size_t need = csrOff + 3200064 + 1024;
    if (ws_size < need) return;  // clean diagnostic fail

    char* ws = (char*)d_ws;
    float* h = (float*)d_out;
    unsigned short* e    = (unsigned short*)ws;
    float*          z    = (float*)(ws + eB);
    unsigned short* hidN = (unsigned short*)(ws + eB + zB);
    float*          hidE = (float*)(ws + eB);          // edge-phase alias
    int* eidx      = (int*)(ws + csrOff);              // 2,400,000 B
    int* counts    = (int*)(ws + csrOff + 2400000);    //   400,000 B
    int* offsets   = (int*)(ws + csrOff + 2800000);    //   400,004 B
    int* blockSums = (int*)(ws + csrOff + 3200064);

    dim3 blk(BLK);
    dim3 gN(2048, 2);
    const int nbE = (E_ + BLK - 1) / BLK;        // 2344
    const int nbScan = (N_ + 1023) / 1024;       // 98

    // ---- CSR build (once; dst is the same for all layers) ----
    hipMemsetAsync(counts, 0, (size_t)N_ * 4, stream);
    hist_k<<<nbE, blk, 0, stream>>>(dst, counts, E_);
    scan1_k<<<nbScan, blk, 0, stream>>>(counts, blockSums, N_);
    scan2_k<<<1, 64, 0, stream>>>(blockSums, nbScan, offsets, N_);
    scan3_k<<<nbScan, blk, 0, stream>>>(counts, blockSums, offsets, N_);
    hipMemsetAsync(counts, 0, (size_t)N_ * 4, stream);  // reuse as cursor
    fill_k<<<nbE, blk, 0, stream>>>(dst, offsets, counts, eidx, E_);

    // ---- 1) h = relu(nf @ Wn + bn) ----
    gemm_rm<0, 0><<<gN, blk, 0, stream>>>(nf, Wn, bn, h, N_, 64, 1);

    // ---- 2) e = relu(ef @ We1 + be1) @ We2 + be2, 4 row-chunks, bf16 out ----
    const int Mc = E_ / 4;  // 150000
    for (int c = 0; c < 4; ++c) {
        const float* efc = ef + (size_t)c * Mc * 16;
        unsigned short* ec = e + (size_t)c * Mc * 128;
        gemm_rm<0, 0><<<gN, blk, 0, stream>>>(efc, We1, be1, hidE, Mc, 16, 1);
        gemm_rm<0, 1><<<gN, blk, 0, stream>>>(hidE, We2, be2, ec, Mc, 128, 0);
    }

    // ---- 3) L GINE layers ----
    const int nbAgg = (N_ + 7) / 8;  // 12500
    for (int l = 0; l < L_; ++l) {
        agg_k<<<nbAgg, blk, 0, stream>>>(h, e, src, eidx, offsets, z, N_);
        gemm_rm<0, 1><<<gN, blk, 0, stream>>>(z, W1 + (size_t)l * 128 * 128,
                                              b1 + (size_t)l * 128, hidN, N_, 128, 1);
        gemm_rm<1, 0><<<gN, blk, 0, stream>>>(hidN, W2 + (size_t)l * 128 * 128,
                                              b2 + (size_t)l * 128, h, N_, 128, 1);
    }
}

// Round 6
// 1175.734 us; speedup vs baseline: 5.0637x; 1.9167x over previous
//
#include <hip/hip_runtime.h>

#define BLK 256

typedef short bf16x8 __attribute__((ext_vector_type(8)));
typedef float f32x4 __attribute__((ext_vector_type(4)));

__device__ __forceinline__ unsigned short f2bf(float f) {
    unsigned int u = __float_as_uint(f);
    u += 0x7FFFu + ((u >> 16) & 1u);
    return (unsigned short)(u >> 16);
}
__device__ __forceinline__ float bf2f(unsigned short s) {
    return __uint_as_float(((unsigned int)s) << 16);
}

// ---------- vector fp32 GEMM (kept for K=64 init and K=16 edge1) ----------
// out[M, half*64 : half*64+64] = (relu?)(in[M,K] @ W[K,128] + bias)[cols]
template <int OUT_BF16>
__global__ __launch_bounds__(BLK) void gemm_rm(
    const float* __restrict__ in, const float* __restrict__ W,
    const float* __restrict__ bias, void* __restrict__ outv,
    int M, int K, int do_relu)
{
    __shared__ float Wl[128 * 64];
    __shared__ float inl[16 * 128];
    __shared__ float bl[64];
    const int tid = threadIdx.x;
    const int half = blockIdx.y;

    for (int idx = tid; idx < K * 64; idx += BLK) {
        int k = idx >> 6, j = idx & 63;
        Wl[idx] = W[k * 128 + half * 64 + j];
    }
    if (tid < 64) bl[tid] = bias[half * 64 + tid];
    __syncthreads();

    const int r  = tid >> 4;
    const int j4 = (tid & 15) << 2;
    const int ntiles = M >> 4;
    const int n4 = (16 * K) >> 2;

    for (int tile = blockIdx.x; tile < ntiles; tile += gridDim.x) {
        const size_t row0 = (size_t)tile << 4;
        const float4* s4 = (const float4*)(in + row0 * K);
        float4* d4 = (float4*)inl;
        for (int idx = tid; idx < n4; idx += BLK) d4[idx] = s4[idx];
        __syncthreads();

        float4 acc = make_float4(bl[j4], bl[j4 + 1], bl[j4 + 2], bl[j4 + 3]);
        const float* a = &inl[r * K];
        #pragma unroll 4
        for (int k = 0; k < K; k += 4) {
            const float4 a4 = *(const float4*)(a + k);
            float4 w;
            w = *(const float4*)(&Wl[(k + 0) * 64 + j4]);
            acc.x += a4.x * w.x; acc.y += a4.x * w.y; acc.z += a4.x * w.z; acc.w += a4.x * w.w;
            w = *(const float4*)(&Wl[(k + 1) * 64 + j4]);
            acc.x += a4.y * w.x; acc.y += a4.y * w.y; acc.z += a4.y * w.z; acc.w += a4.y * w.w;
            w = *(const float4*)(&Wl[(k + 2) * 64 + j4]);
            acc.x += a4.z * w.x; acc.y += a4.z * w.y; acc.z += a4.z * w.z; acc.w += a4.z * w.w;
            w = *(const float4*)(&Wl[(k + 3) * 64 + j4]);
            acc.x += a4.w * w.x; acc.y += a4.w * w.y; acc.z += a4.w * w.z; acc.w += a4.w * w.w;
        }
        if (do_relu) {
            acc.x = fmaxf(acc.x, 0.f); acc.y = fmaxf(acc.y, 0.f);
            acc.z = fmaxf(acc.z, 0.f); acc.w = fmaxf(acc.w, 0.f);
        }
        const size_t o = (row0 + r) * 128 + half * 64 + j4;
        if (OUT_BF16) {
            ushort4 ob;
            ob.x = f2bf(acc.x); ob.y = f2bf(acc.y);
            ob.z = f2bf(acc.z); ob.w = f2bf(acc.w);
            *(ushort4*)((unsigned short*)outv + o) = ob;
        } else {
            *(float4*)((float*)outv + o) = acc;
        }
        __syncthreads();
    }
}

// ---------- weight prep: W[128][128] f32 -> transposed, XOR-swizzled hi/lo bf16 ----------
// slot 0 = We2, 1..4 = W1[l], 5..8 = W2[l].  Element (k,n) of W stored at
// ushort index n*128 + (k ^ ((n&7)<<3)); hi at slot base, lo at +16384.
__global__ __launch_bounds__(BLK) void prep_w(
    const float* __restrict__ We2, const float* __restrict__ W1,
    const float* __restrict__ W2, unsigned short* __restrict__ wp)
{
    const int slot = blockIdx.y;
    const float* Wsrc = (slot == 0) ? We2
                      : (slot <= 4 ? W1 + (size_t)(slot - 1) * 16384
                                   : W2 + (size_t)(slot - 5) * 16384);
    const int i = blockIdx.x * BLK + threadIdx.x;   // 0..16383 (grid.x = 64)
    const int k = i >> 7, n = i & 127;
    const float f = Wsrc[k * 128 + n];
    const unsigned short hi = f2bf(f);
    const unsigned short lo = f2bf(f - bf2f(hi));
    const int idx = n * 128 + (k ^ ((n & 7) << 3));
    unsigned short* base = wp + (size_t)slot * 32768;
    base[idx] = hi;
    base[16384 + idx] = lo;
}

// ---------- MFMA GEMM: out = (relu?)(A[M,128] @ W[128,128] + bias) ----------
// Block = 4 waves; wave computes 32 rows x 128 cols. Weights (hi+lo) staged
// linearly into 64 KB LDS from the pre-swizzled global buffer.
template <int A_BF16, int OUT_BF16>
__global__ __launch_bounds__(BLK) void gemm128(
    const void* __restrict__ Av, const unsigned short* __restrict__ Wp,
    const float* __restrict__ bias, void* __restrict__ outv,
    int M, int do_relu)
{
    __shared__ unsigned short Bl[32768];    // 64 KB: hi [0,16384), lo [16384,32768)
    const int tid = threadIdx.x;
    {
        const float4* s = (const float4*)Wp;
        float4* d = (float4*)Bl;
        #pragma unroll
        for (int i = 0; i < 16; ++i) d[tid + i * BLK] = s[tid + i * BLK];
    }
    __syncthreads();

    const int lane = tid & 63;
    const int wv   = tid >> 6;        // wave 0..3
    const int l15  = lane & 15;
    const int g    = lane >> 4;       // 0..3
    const int wbase = wv * 32;

    float bcol[8];
    #pragma unroll
    for (int cf = 0; cf < 8; ++cf) bcol[cf] = bias[cf * 16 + l15];

    const int ntiles = (M + 127) >> 7;
    for (int tile = blockIdx.x; tile < ntiles; tile += gridDim.x) {
        // ---- load A fragments: row = lane&15 (+16 per rf), k = ks*32 + g*8 + j ----
        bf16x8 af[2][4];
        #pragma unroll
        for (int rf = 0; rf < 2; ++rf) {
            const int row = tile * 128 + wbase + rf * 16 + l15;
            const bool ok = row < M;
            #pragma unroll
            for (int ks = 0; ks < 4; ++ks) {
                const int k0 = ks * 32 + g * 8;
                if (A_BF16) {
                    af[rf][ks] = ok
                        ? *(const bf16x8*)((const unsigned short*)Av + (size_t)row * 128 + k0)
                        : (bf16x8)0;
                } else {
                    if (ok) {
                        const float* ap = (const float*)Av + (size_t)row * 128 + k0;
                        const float4 f0 = *(const float4*)(ap);
                        const float4 f1 = *(const float4*)(ap + 4);
                        bf16x8 a;
                        a[0] = (short)f2bf(f0.x); a[1] = (short)f2bf(f0.y);
                        a[2] = (short)f2bf(f0.z); a[3] = (short)f2bf(f0.w);
                        a[4] = (short)f2bf(f1.x); a[5] = (short)f2bf(f1.y);
                        a[6] = (short)f2bf(f1.z); a[7] = (short)f2bf(f1.w);
                        af[rf][ks] = a;
                    } else af[rf][ks] = (bf16x8)0;
                }
            }
        }
        // ---- accumulate ----
        f32x4 acc[2][8];
        #pragma unroll
        for (int rf = 0; rf < 2; ++rf)
            #pragma unroll
            for (int cf = 0; cf < 8; ++cf) {
                const float b = bcol[cf];
                acc[rf][cf][0] = b; acc[rf][cf][1] = b;
                acc[rf][cf][2] = b; acc[rf][cf][3] = b;
            }
        #pragma unroll
        for (int ks = 0; ks < 4; ++ks) {
            #pragma unroll
            for (int cf = 0; cf < 8; ++cf) {
                const int c = cf * 16 + l15;
                const int ku = (ks * 32 + g * 8) ^ ((c & 7) << 3);
                const bf16x8 bh = *(const bf16x8*)(&Bl[c * 128 + ku]);
                const bf16x8 bl = *(const bf16x8*)(&Bl[16384 + c * 128 + ku]);
                acc[0][cf] = __builtin_amdgcn_mfma_f32_16x16x32_bf16(af[0][ks], bh, acc[0][cf], 0, 0, 0);
                acc[1][cf] = __builtin_amdgcn_mfma_f32_16x16x32_bf16(af[1][ks], bh, acc[1][cf], 0, 0, 0);
                acc[0][cf] = __builtin_amdgcn_mfma_f32_16x16x32_bf16(af[0][ks], bl, acc[0][cf], 0, 0, 0);
                acc[1][cf] = __builtin_amdgcn_mfma_f32_16x16x32_bf16(af[1][ks], bl, acc[1][cf], 0, 0, 0);
            }
        }
        // ---- epilogue: D row = g*4 + reg (within frag), col = lane&15 ----
        #pragma unroll
        for (int rf = 0; rf < 2; ++rf) {
            const int r0 = tile * 128 + wbase + rf * 16 + g * 4;
            #pragma unroll
            for (int cf = 0; cf < 8; ++cf) {
                const int col = cf * 16 + l15;
                const f32x4 v = acc[rf][cf];
                #pragma unroll
                for (int j = 0; j < 4; ++j) {
                    const int row = r0 + j;
                    if (row < M) {
                        float x = v[j];
                        if (do_relu) x = fmaxf(x, 0.f);
                        if (OUT_BF16)
                            ((unsigned short*)outv)[(size_t)row * 128 + col] = f2bf(x);
                        else
                            ((float*)outv)[(size_t)row * 128 + col] = x;
                    }
                }
            }
        }
    }
}

// ---------- CSR build ----------
__global__ __launch_bounds__(BLK) void hist_k(
    const int* __restrict__ dst, int* __restrict__ counts, int nE)
{
    int i = blockIdx.x * BLK + threadIdx.x;
    if (i < nE) atomicAdd(&counts[dst[i]], 1);
}

__global__ __launch_bounds__(BLK) void scan1_k(
    const int* __restrict__ counts, int* __restrict__ blockSums, int n)
{
    __shared__ int s[BLK];
    const int t = threadIdx.x, b = blockIdx.x;
    const int base = b * 1024 + t * 4;
    int sum = 0;
    #pragma unroll
    for (int j = 0; j < 4; ++j) { int i = base + j; if (i < n) sum += counts[i]; }
    s[t] = sum; __syncthreads();
    for (int off = 128; off > 0; off >>= 1) {
        if (t < off) s[t] += s[t + off];
        __syncthreads();
    }
    if (t == 0) blockSums[b] = s[0];
}

__global__ void scan2_k(int* __restrict__ blockSums, int nb,
                        int* __restrict__ offsets, int n)
{
    if (threadIdx.x == 0 && blockIdx.x == 0) {
        int run = 0;
        for (int i = 0; i < nb; ++i) { int v = blockSums[i]; blockSums[i] = run; run += v; }
        offsets[n] = run;
    }
}

__global__ __launch_bounds__(BLK) void scan3_k(
    const int* __restrict__ counts, const int* __restrict__ blockSums,
    int* __restrict__ offsets, int n)
{
    __shared__ int s[BLK];
    const int t = threadIdx.x, b = blockIdx.x;
    const int base = b * 1024 + t * 4;
    int c[4]; int tsum = 0;
    #pragma unroll
    for (int j = 0; j < 4; ++j) {
        c[j] = (base + j < n) ? counts[base + j] : 0;
        tsum += c[j];
    }
    s[t] = tsum; __syncthreads();
    for (int off = 1; off < BLK; off <<= 1) {
        int v = (t >= off) ? s[t - off] : 0;
        __syncthreads();
        s[t] += v;
        __syncthreads();
    }
    int run = s[t] - tsum + blockSums[b];
    #pragma unroll
    for (int j = 0; j < 4; ++j) {
        if (base + j < n) { offsets[base + j] = run; run += c[j]; }
    }
}

__global__ __launch_bounds__(BLK) void fill_k(
    const int* __restrict__ dst, const int* __restrict__ offsets,
    int* __restrict__ cursor, int* __restrict__ eidx, int nE)
{
    int i = blockIdx.x * BLK + threadIdx.x;
    if (i < nE) {
        int d = dst[i];
        int pos = offsets[d] + atomicAdd(&cursor[d], 1);
        eidx[pos] = i;
    }
}

// ---- fused aggregation: z[n] = h[n] + sum_{e in CSR[n]} relu(h[src[e]] + e) ----
__global__ __launch_bounds__(BLK) void agg_k(
    const float* __restrict__ h, const unsigned short* __restrict__ e,
    const int* __restrict__ srcv, const int* __restrict__ eidx,
    const int* __restrict__ offsets, float* __restrict__ z, int nN)
{
    const int t = threadIdx.x;
    const int node = blockIdx.x * 8 + (t >> 5);
    if (node >= nN) return;
    const int c4 = (t & 31) << 2;
    float4 acc = *(const float4*)(h + (size_t)node * 128 + c4);
    const int beg = offsets[node], end = offsets[node + 1];
    for (int i = beg; i < end; ++i) {
        const int eg = eidx[i];
        const int s = srcv[eg];
        const float4 hv = *(const float4*)(h + (size_t)s * 128 + c4);
        const ushort4 ev = *(const ushort4*)(e + (size_t)eg * 128 + c4);
        acc.x += fmaxf(hv.x + bf2f(ev.x), 0.f);
        acc.y += fmaxf(hv.y + bf2f(ev.y), 0.f);
        acc.z += fmaxf(hv.z + bf2f(ev.z), 0.f);
        acc.w += fmaxf(hv.w + bf2f(ev.w), 0.f);
    }
    *(float4*)(z + (size_t)node * 128 + c4) = acc;
}

extern "C" void kernel_launch(void* const* d_in, const int* in_sizes, int n_in,
                              void* d_out, int out_size, void* d_ws, size_t ws_size,
                              hipStream_t stream) {
    const float* nf  = (const float*)d_in[0];
    const float* ef  = (const float*)d_in[1];
    const int*   src = (const int*)d_in[2];
    const int*   dst = (const int*)d_in[3];
    const float* Wn  = (const float*)d_in[4];
    const float* bn  = (const float*)d_in[5];
    const float* We1 = (const float*)d_in[6];
    const float* be1 = (const float*)d_in[7];
    const float* We2 = (const float*)d_in[8];
    const float* be2 = (const float*)d_in[9];
    const float* W1  = (const float*)d_in[10];
    const float* b1  = (const float*)d_in[11];
    const float* W2  = (const float*)d_in[12];
    const float* b2  = (const float*)d_in[13];

    const int N_ = 100000, E_ = 600000, L_ = 4;

    // workspace layout (~234.2 MB):
    //   e    bf16 [E,128] 153.6 MB @ 0
    //   z    f32  [N,128]  51.2 MB @ eB        (aliased by hidE during edge phase)
    //   hidN bf16 [N,128]  25.6 MB @ eB+zB
    //   CSR: eidx 2.4 MB | counts 0.4 | offsets 0.4 | blockSums @ csrOff
    //   wprep: 9 slots x 64 KB (hi/lo bf16, transposed+swizzled) @ wpOff
    const size_t eB  = (size_t)E_ * 128 * 2;   // 153,600,000
    const size_t zB  = (size_t)N_ * 128 * 4;   //  51,200,000
    const size_t hnB = (size_t)N_ * 128 * 2;   //  25,600,000
    const size_t csrOff = eB + zB + hnB;       // 230,400,000
    const size_t wpOff  = csrOff + 3200064 + 1024;
    const size_t need = wpOff + 9 * 65536;
    if (ws_size < need) return;

    char* ws = (char*)d_ws;
    float* h = (float*)d_out;
    unsigned short* e    = (unsigned short*)ws;
    float*          z    = (float*)(ws + eB);
    unsigned short* hidN = (unsigned short*)(ws + eB + zB);
    unsigned short* hidE = (unsigned short*)(ws + eB);   // edge-phase alias of z
    int* eidx      = (int*)(ws + csrOff);
    int* counts    = (int*)(ws + csrOff + 2400000);
    int* offsets   = (int*)(ws + csrOff + 2800000);
    int* blockSums = (int*)(ws + csrOff + 3200064);
    unsigned short* wp = (unsigned short*)(ws + wpOff);

    dim3 blk(BLK);
    dim3 gN(2048, 2);
    const int nbE = (E_ + BLK - 1) / BLK;
    const int nbScan = (N_ + 1023) / 1024;

    // weight prep (9 x 128x128 -> hi/lo swizzled)
    prep_w<<<dim3(64, 9), blk, 0, stream>>>(We2, W1, W2, wp);

    // CSR build (dst layer-invariant)
    hipMemsetAsync(counts, 0, (size_t)N_ * 4, stream);
    hist_k<<<nbE, blk, 0, stream>>>(dst, counts, E_);
    scan1_k<<<nbScan, blk, 0, stream>>>(counts, blockSums, N_);
    scan2_k<<<1, 64, 0, stream>>>(blockSums, nbScan, offsets, N_);
    scan3_k<<<nbScan, blk, 0, stream>>>(counts, blockSums, offsets, N_);
    hipMemsetAsync(counts, 0, (size_t)N_ * 4, stream);
    fill_k<<<nbE, blk, 0, stream>>>(dst, offsets, counts, eidx, E_);

    // 1) h = relu(nf @ Wn + bn)   (K=64, vector fp32)
    gemm_rm<0><<<gN, blk, 0, stream>>>(nf, Wn, bn, h, N_, 64, 1);

    // 2) e = relu(ef @ We1 + be1) @ We2 + be2, 4 row-chunks
    const int Mc = E_ / 4;  // 150000
    const int gxE = 1024;   // min(1172 tiles, 1024)
    for (int c = 0; c < 4; ++c) {
        const float* efc = ef + (size_t)c * Mc * 16;
        unsigned short* ec = e + (size_t)c * Mc * 128;
        gemm_rm<1><<<gN, blk, 0, stream>>>(efc, We1, be1, hidE, Mc, 16, 1);
        gemm128<1, 1><<<dim3(gxE), blk, 0, stream>>>(hidE, wp, be2, ec, Mc, 0);
    }

    // 3) L GINE layers (MFMA GEMMs)
    const int nbAgg = (N_ + 7) / 8;
    const int gxN = (N_ + 127) / 128;   // 782
    for (int l = 0; l < L_; ++l) {
        agg_k<<<nbAgg, blk, 0, stream>>>(h, e, src, eidx, offsets, z, N_);
        gemm128<0, 1><<<dim3(gxN), blk, 0, stream>>>(
            z, wp + (size_t)(1 + l) * 32768, b1 + (size_t)l * 128, hidN, N_, 1);
        gemm128<1, 0><<<dim3(gxN), blk, 0, stream>>>(
            hidN, wp + (size_t)(5 + l) * 32768, b2 + (size_t)l * 128, h, N_, 1);
    }
}

// Round 7
// 1052.926 us; speedup vs baseline: 5.6543x; 1.1166x over previous
//
#include <hip/hip_runtime.h>

#define BLK 256

typedef short bf16x8 __attribute__((ext_vector_type(8)));
typedef float f32x4 __attribute__((ext_vector_type(4)));

__device__ __forceinline__ unsigned short f2bf(float f) {
    unsigned int u = __float_as_uint(f);
    u += 0x7FFFu + ((u >> 16) & 1u);
    return (unsigned short)(u >> 16);
}
__device__ __forceinline__ float bf2f(unsigned short s) {
    return __uint_as_float(((unsigned int)s) << 16);
}

// ---------- slim K=16 fp32 GEMM (edge MLP layer 1), bf16 out ----------
__global__ __launch_bounds__(BLK) void gemm_rm16(
    const float* __restrict__ in, const float* __restrict__ W,
    const float* __restrict__ bias, unsigned short* __restrict__ out, int M)
{
    __shared__ float Wl[16 * 64];
    __shared__ float inl[16 * 16];
    __shared__ float bl[64];
    const int tid = threadIdx.x;
    const int half = blockIdx.y;

    for (int idx = tid; idx < 16 * 64; idx += BLK) {
        int k = idx >> 6, j = idx & 63;
        Wl[idx] = W[k * 128 + half * 64 + j];
    }
    if (tid < 64) bl[tid] = bias[half * 64 + tid];
    __syncthreads();

    const int r  = tid >> 4;
    const int j4 = (tid & 15) << 2;
    const int ntiles = M >> 4;

    for (int tile = blockIdx.x; tile < ntiles; tile += gridDim.x) {
        const size_t row0 = (size_t)tile << 4;
        if (tid < 64) ((float4*)inl)[tid] = ((const float4*)(in + row0 * 16))[tid];
        __syncthreads();

        float4 acc = make_float4(bl[j4], bl[j4 + 1], bl[j4 + 2], bl[j4 + 3]);
        const float* a = &inl[r * 16];
        #pragma unroll
        for (int k = 0; k < 16; k += 4) {
            const float4 a4 = *(const float4*)(a + k);
            float4 w;
            w = *(const float4*)(&Wl[(k + 0) * 64 + j4]);
            acc.x += a4.x * w.x; acc.y += a4.x * w.y; acc.z += a4.x * w.z; acc.w += a4.x * w.w;
            w = *(const float4*)(&Wl[(k + 1) * 64 + j4]);
            acc.x += a4.y * w.x; acc.y += a4.y * w.y; acc.z += a4.y * w.z; acc.w += a4.y * w.w;
            w = *(const float4*)(&Wl[(k + 2) * 64 + j4]);
            acc.x += a4.z * w.x; acc.y += a4.z * w.y; acc.z += a4.z * w.z; acc.w += a4.z * w.w;
            w = *(const float4*)(&Wl[(k + 3) * 64 + j4]);
            acc.x += a4.w * w.x; acc.y += a4.w * w.y; acc.z += a4.w * w.z; acc.w += a4.w * w.w;
        }
        ushort4 ob;
        ob.x = f2bf(fmaxf(acc.x, 0.f)); ob.y = f2bf(fmaxf(acc.y, 0.f));
        ob.z = f2bf(fmaxf(acc.z, 0.f)); ob.w = f2bf(fmaxf(acc.w, 0.f));
        *(ushort4*)(out + (row0 + r) * 128 + half * 64 + j4) = ob;
        __syncthreads();
    }
}

// ---------- weight prep: W[K][128] f32 -> transposed, XOR-swizzled hi/lo bf16 ----------
// slot 0 = We2 (K=128), 1..4 = W1[l], 5..8 = W2[l], 9 = Wn (K=64).
// Element (k,n) stored at ushort idx n*K + (k ^ ((n&7)<<3)); hi at base, lo at +K*128.
__global__ __launch_bounds__(BLK) void prep_w(
    const float* __restrict__ Wn, const float* __restrict__ We2,
    const float* __restrict__ W1, const float* __restrict__ W2,
    unsigned short* __restrict__ wp)
{
    const int slot = blockIdx.y;
    const int K = (slot == 9) ? 64 : 128;
    const float* Wsrc = (slot == 0) ? We2
                      : (slot <= 4) ? W1 + (size_t)(slot - 1) * 16384
                      : (slot <= 8) ? W2 + (size_t)(slot - 5) * 16384
                      : Wn;
    const int i = blockIdx.x * BLK + threadIdx.x;
    if (i >= K * 128) return;
    const int k = i >> 7, n = i & 127;
    const float f = Wsrc[k * 128 + n];
    const unsigned short hi = f2bf(f);
    const unsigned short lo = f2bf(f - bf2f(hi));
    const int idx = n * K + (k ^ ((n & 7) << 3));
    unsigned short* base = wp + (size_t)slot * 32768;
    base[idx] = hi;
    base[K * 128 + idx] = lo;
}

// ---------- MFMA GEMM: out = (relu?)(A[M,KDIM] @ W[KDIM,128] + bias) ----------
// Block = 4 waves; wave computes 32 rows x 128 cols. Weights (hi+lo bf16)
// staged linearly into LDS from the pre-swizzled global buffer.
template <int KDIM, int A_BF16, int OUT_BF16>
__global__ __launch_bounds__(BLK) void gemm128(
    const void* __restrict__ Av, const unsigned short* __restrict__ Wp,
    const float* __restrict__ bias, void* __restrict__ outv,
    int M, int do_relu)
{
    __shared__ unsigned short Bl[2 * KDIM * 128];   // hi [0,K*128), lo [K*128,...)
    const int tid = threadIdx.x;
    {
        const float4* s = (const float4*)Wp;
        float4* d = (float4*)Bl;
        #pragma unroll
        for (int i = 0; i < KDIM / 8; ++i) d[tid + i * BLK] = s[tid + i * BLK];
    }
    __syncthreads();

    const int lane = tid & 63;
    const int wv   = tid >> 6;
    const int l15  = lane & 15;
    const int g    = lane >> 4;
    const int wbase = wv * 32;
    const int NKS = KDIM / 32;

    float bcol[8];
    #pragma unroll
    for (int cf = 0; cf < 8; ++cf) bcol[cf] = bias[cf * 16 + l15];

    const int ntiles = (M + 127) >> 7;
    for (int tile = blockIdx.x; tile < ntiles; tile += gridDim.x) {
        bf16x8 af[2][KDIM / 32];
        #pragma unroll
        for (int rf = 0; rf < 2; ++rf) {
            const int row = tile * 128 + wbase + rf * 16 + l15;
            const bool ok = row < M;
            #pragma unroll
            for (int ks = 0; ks < NKS; ++ks) {
                const int k0 = ks * 32 + g * 8;
                if (A_BF16) {
                    af[rf][ks] = ok
                        ? *(const bf16x8*)((const unsigned short*)Av + (size_t)row * KDIM + k0)
                        : (bf16x8)0;
                } else {
                    if (ok) {
                        const float* ap = (const float*)Av + (size_t)row * KDIM + k0;
                        const float4 f0 = *(const float4*)(ap);
                        const float4 f1 = *(const float4*)(ap + 4);
                        bf16x8 a;
                        a[0] = (short)f2bf(f0.x); a[1] = (short)f2bf(f0.y);
                        a[2] = (short)f2bf(f0.z); a[3] = (short)f2bf(f0.w);
                        a[4] = (short)f2bf(f1.x); a[5] = (short)f2bf(f1.y);
                        a[6] = (short)f2bf(f1.z); a[7] = (short)f2bf(f1.w);
                        af[rf][ks] = a;
                    } else af[rf][ks] = (bf16x8)0;
                }
            }
        }
        f32x4 acc[2][8];
        #pragma unroll
        for (int rf = 0; rf < 2; ++rf)
            #pragma unroll
            for (int cf = 0; cf < 8; ++cf) {
                const float b = bcol[cf];
                acc[rf][cf][0] = b; acc[rf][cf][1] = b;
                acc[rf][cf][2] = b; acc[rf][cf][3] = b;
            }
        #pragma unroll
        for (int ks = 0; ks < NKS; ++ks) {
            #pragma unroll
            for (int cf = 0; cf < 8; ++cf) {
                const int c = cf * 16 + l15;
                const int ku = (ks * 32 + g * 8) ^ ((c & 7) << 3);
                const bf16x8 bh = *(const bf16x8*)(&Bl[c * KDIM + ku]);
                const bf16x8 blo = *(const bf16x8*)(&Bl[KDIM * 128 + c * KDIM + ku]);
                acc[0][cf] = __builtin_amdgcn_mfma_f32_16x16x32_bf16(af[0][ks], bh, acc[0][cf], 0, 0, 0);
                acc[1][cf] = __builtin_amdgcn_mfma_f32_16x16x32_bf16(af[1][ks], bh, acc[1][cf], 0, 0, 0);
                acc[0][cf] = __builtin_amdgcn_mfma_f32_16x16x32_bf16(af[0][ks], blo, acc[0][cf], 0, 0, 0);
                acc[1][cf] = __builtin_amdgcn_mfma_f32_16x16x32_bf16(af[1][ks], blo, acc[1][cf], 0, 0, 0);
            }
        }
        #pragma unroll
        for (int rf = 0; rf < 2; ++rf) {
            const int r0 = tile * 128 + wbase + rf * 16 + g * 4;
            #pragma unroll
            for (int cf = 0; cf < 8; ++cf) {
                const int col = cf * 16 + l15;
                const f32x4 v = acc[rf][cf];
                #pragma unroll
                for (int j = 0; j < 4; ++j) {
                    const int row = r0 + j;
                    if (row < M) {
                        float x = v[j];
                        if (do_relu) x = fmaxf(x, 0.f);
                        if (OUT_BF16)
                            ((unsigned short*)outv)[(size_t)row * 128 + col] = f2bf(x);
                        else
                            ((float*)outv)[(size_t)row * 128 + col] = x;
                    }
                }
            }
        }
    }
}

// ---------- CSR build ----------
__global__ __launch_bounds__(BLK) void hist_k(
    const int* __restrict__ dst, int* __restrict__ counts, int nE)
{
    int i = blockIdx.x * BLK + threadIdx.x;
    if (i < nE) atomicAdd(&counts[dst[i]], 1);
}

__global__ __launch_bounds__(BLK) void scan1_k(
    const int* __restrict__ counts, int* __restrict__ blockSums, int n)
{
    __shared__ int s[BLK];
    const int t = threadIdx.x, b = blockIdx.x;
    const int base = b * 1024 + t * 4;
    int sum = 0;
    #pragma unroll
    for (int j = 0; j < 4; ++j) { int i = base + j; if (i < n) sum += counts[i]; }
    s[t] = sum; __syncthreads();
    for (int off = 128; off > 0; off >>= 1) {
        if (t < off) s[t] += s[t + off];
        __syncthreads();
    }
    if (t == 0) blockSums[b] = s[0];
}

__global__ void scan2_k(int* __restrict__ blockSums, int nb,
                        int* __restrict__ offsets, int n)
{
    if (threadIdx.x == 0 && blockIdx.x == 0) {
        int run = 0;
        for (int i = 0; i < nb; ++i) { int v = blockSums[i]; blockSums[i] = run; run += v; }
        offsets[n] = run;
    }
}

__global__ __launch_bounds__(BLK) void scan3_k(
    const int* __restrict__ counts, const int* __restrict__ blockSums,
    int* __restrict__ offsets, int n)
{
    __shared__ int s[BLK];
    const int t = threadIdx.x, b = blockIdx.x;
    const int base = b * 1024 + t * 4;
    int c[4]; int tsum = 0;
    #pragma unroll
    for (int j = 0; j < 4; ++j) {
        c[j] = (base + j < n) ? counts[base + j] : 0;
        tsum += c[j];
    }
    s[t] = tsum; __syncthreads();
    for (int off = 1; off < BLK; off <<= 1) {
        int v = (t >= off) ? s[t - off] : 0;
        __syncthreads();
        s[t] += v;
        __syncthreads();
    }
    int run = s[t] - tsum + blockSums[b];
    #pragma unroll
    for (int j = 0; j < 4; ++j) {
        if (base + j < n) { offsets[base + j] = run; run += c[j]; }
    }
}

__global__ __launch_bounds__(BLK) void fill_k(
    const int* __restrict__ dst, const int* __restrict__ offsets,
    int* __restrict__ cursor, int* __restrict__ eidx, int nE)
{
    int i = blockIdx.x * BLK + threadIdx.x;
    if (i < nE) {
        int d = dst[i];
        int pos = offsets[d] + atomicAdd(&cursor[d], 1);
        eidx[pos] = i;
    }
}

// permute edge inputs into CSR order: ef_perm[pos] = ef[eidx[pos]] (16 f32),
// src_perm[pos] = src[eidx[pos]].  4 threads per pos.
__global__ __launch_bounds__(BLK) void perm_k(
    const float* __restrict__ ef, const int* __restrict__ src,
    const int* __restrict__ eidx, float* __restrict__ ef_perm,
    int* __restrict__ src_perm, int nE)
{
    int i = blockIdx.x * BLK + threadIdx.x;
    if (i >= nE * 4) return;
    const int pos = i >> 2, part = i & 3;
    const int eg = eidx[pos];
    ((float4*)(ef_perm + (size_t)pos * 16))[part] =
        ((const float4*)(ef + (size_t)eg * 16))[part];
    if (part == 0) src_perm[pos] = src[eg];
}

// ---- aggregation: z[n] = h[n] + sum_{i in [off[n],off[n+1])} relu(h[sp[i]] + e[i]) ----
// e and src_perm are CSR-ordered -> sequential; only h gathers are random (L3).
__global__ __launch_bounds__(BLK) void agg_k(
    const float* __restrict__ h, const unsigned short* __restrict__ e,
    const int* __restrict__ src_perm, const int* __restrict__ offsets,
    float* __restrict__ z, int nN)
{
    const int t = threadIdx.x;
    const int node = blockIdx.x * 8 + (t >> 5);
    if (node >= nN) return;
    const int c4 = (t & 31) << 2;
    float4 acc = *(const float4*)(h + (size_t)node * 128 + c4);
    const int beg = offsets[node], end = offsets[node + 1];
    for (int i = beg; i < end; ++i) {
        const int s = src_perm[i];
        const float4 hv = *(const float4*)(h + (size_t)s * 128 + c4);
        const ushort4 ev = *(const ushort4*)(e + (size_t)i * 128 + c4);
        acc.x += fmaxf(hv.x + bf2f(ev.x), 0.f);
        acc.y += fmaxf(hv.y + bf2f(ev.y), 0.f);
        acc.z += fmaxf(hv.z + bf2f(ev.z), 0.f);
        acc.w += fmaxf(hv.w + bf2f(ev.w), 0.f);
    }
    *(float4*)(z + (size_t)node * 128 + c4) = acc;
}

extern "C" void kernel_launch(void* const* d_in, const int* in_sizes, int n_in,
                              void* d_out, int out_size, void* d_ws, size_t ws_size,
                              hipStream_t stream) {
    const float* nf  = (const float*)d_in[0];
    const float* ef  = (const float*)d_in[1];
    const int*   src = (const int*)d_in[2];
    const int*   dst = (const int*)d_in[3];
    const float* Wn  = (const float*)d_in[4];
    const float* bn  = (const float*)d_in[5];
    const float* We1 = (const float*)d_in[6];
    const float* be1 = (const float*)d_in[7];
    const float* We2 = (const float*)d_in[8];
    const float* be2 = (const float*)d_in[9];
    const float* W1  = (const float*)d_in[10];
    const float* b1  = (const float*)d_in[11];
    const float* W2  = (const float*)d_in[12];
    const float* b2  = (const float*)d_in[13];

    const int N_ = 100000, E_ = 600000, L_ = 4;

    // workspace (~236.7 MB; known-safe budget 256 MB):
    //   e bf16 [E,128] (CSR order)      153.6 MB @ 0
    //   layer phase: z f32 [N,128] 51.2 @ eB ; hidN bf16 [N,128] 25.6 @ eB+zB
    //   edge  phase: ef_perm f32 [E,16] 38.4 @ eB ; hidE bf16 [E/4,128] 38.4 @ eB+38.4M
    //   CSR: eidx | counts | offsets | blockSums | src_perm  @ csrOff
    //   wp: 10 weight slots (hi/lo bf16, transposed+swizzled) @ wpOff
    const size_t eB  = (size_t)E_ * 128 * 2;   // 153,600,000
    const size_t zB  = (size_t)N_ * 128 * 4;   //  51,200,000
    const size_t hnB = (size_t)N_ * 128 * 2;   //  25,600,000
    const size_t csrOff = eB + zB + hnB;       // 230,400,000
    const size_t wpOff  = csrOff + 5601088;
    const size_t need = wpOff + 10 * 65536;
    if (ws_size < need) return;

    char* ws = (char*)d_ws;
    float* h = (float*)d_out;
    unsigned short* e    = (unsigned short*)ws;
    float*          z    = (float*)(ws + eB);
    unsigned short* hidN = (unsigned short*)(ws + eB + zB);
    float*          ef_perm = (float*)(ws + eB);                    // edge-phase alias
    unsigned short* hidE = (unsigned short*)(ws + eB + 38400000);   // edge-phase alias
    int* eidx      = (int*)(ws + csrOff);
    int* counts    = (int*)(ws + csrOff + 2400000);
    int* offsets   = (int*)(ws + csrOff + 2800000);
    int* blockSums = (int*)(ws + csrOff + 3200064);
    int* src_perm  = (int*)(ws + csrOff + 3201088);
    unsigned short* wp = (unsigned short*)(ws + wpOff);

    dim3 blk(BLK);
    const int nbE = (E_ + BLK - 1) / BLK;
    const int nbScan = (N_ + 1023) / 1024;

    // weight prep (10 slots)
    prep_w<<<dim3(64, 10), blk, 0, stream>>>(Wn, We2, W1, W2, wp);

    // CSR build (dst layer-invariant)
    hipMemsetAsync(counts, 0, (size_t)N_ * 4, stream);
    hist_k<<<nbE, blk, 0, stream>>>(dst, counts, E_);
    scan1_k<<<nbScan, blk, 0, stream>>>(counts, blockSums, N_);
    scan2_k<<<1, 64, 0, stream>>>(blockSums, nbScan, offsets, N_);
    scan3_k<<<nbScan, blk, 0, stream>>>(counts, blockSums, offsets, N_);
    hipMemsetAsync(counts, 0, (size_t)N_ * 4, stream);
    fill_k<<<nbE, blk, 0, stream>>>(dst, offsets, counts, eidx, E_);

    // permute edge inputs into CSR order
    perm_k<<<(E_ * 4 + BLK - 1) / BLK, blk, 0, stream>>>(
        ef, src, eidx, ef_perm, src_perm, E_);

    // 1) h = relu(nf @ Wn + bn)   (K=64 MFMA)
    const int gxN = (N_ + 127) / 128;   // 782
    gemm128<64, 0, 0><<<dim3(gxN), blk, 0, stream>>>(
        nf, wp + (size_t)9 * 32768, bn, h, N_, 1);

    // 2) e = relu(ef_perm @ We1 + be1) @ We2 + be2, 4 row-chunks, CSR order
    const int Mc = E_ / 4;  // 150000
    const int gxE = 1024;
    for (int c = 0; c < 4; ++c) {
        const float* efc = ef_perm + (size_t)c * Mc * 16;
        unsigned short* ec = e + (size_t)c * Mc * 128;
        gemm_rm16<<<dim3(2048, 2), blk, 0, stream>>>(efc, We1, be1, hidE, Mc);
        gemm128<128, 1, 1><<<dim3(gxE), blk, 0, stream>>>(hidE, wp, be2, ec, Mc, 0);
    }

    // 3) L GINE layers
    const int nbAgg = (N_ + 7) / 8;
    for (int l = 0; l < L_; ++l) {
        agg_k<<<nbAgg, blk, 0, stream>>>(h, e, src_perm, offsets, z, N_);
        gemm128<128, 0, 1><<<dim3(gxN), blk, 0, stream>>>(
            z, wp + (size_t)(1 + l) * 32768, b1 + (size_t)l * 128, hidN, N_, 1);
        gemm128<128, 1, 0><<<dim3(gxN), blk, 0, stream>>>(
            hidN, wp + (size_t)(5 + l) * 32768, b2 + (size_t)l * 128, h, N_, 1);
    }
}

// Round 8
// 891.696 us; speedup vs baseline: 6.6766x; 1.1808x over previous
//
#include <hip/hip_runtime.h>

#define BLK 256

typedef short bf16x8 __attribute__((ext_vector_type(8)));
typedef float f32x4 __attribute__((ext_vector_type(4)));

__device__ __forceinline__ unsigned short f2bf(float f) {
    unsigned int u = __float_as_uint(f);
    u += 0x7FFFu + ((u >> 16) & 1u);
    return (unsigned short)(u >> 16);
}
__device__ __forceinline__ float bf2f(unsigned short s) {
    return __uint_as_float(((unsigned int)s) << 16);
}

// ---------- slim K=16 fp32 GEMM (edge MLP layer 1), bf16 out ----------
__global__ __launch_bounds__(BLK) void gemm_rm16(
    const float* __restrict__ in, const float* __restrict__ W,
    const float* __restrict__ bias, unsigned short* __restrict__ out, int M)
{
    __shared__ float Wl[16 * 64];
    __shared__ float inl[16 * 16];
    __shared__ float bl[64];
    const int tid = threadIdx.x;
    const int half = blockIdx.y;

    for (int idx = tid; idx < 16 * 64; idx += BLK) {
        int k = idx >> 6, j = idx & 63;
        Wl[idx] = W[k * 128 + half * 64 + j];
    }
    if (tid < 64) bl[tid] = bias[half * 64 + tid];
    __syncthreads();

    const int r  = tid >> 4;
    const int j4 = (tid & 15) << 2;
    const int ntiles = M >> 4;

    for (int tile = blockIdx.x; tile < ntiles; tile += gridDim.x) {
        const size_t row0 = (size_t)tile << 4;
        if (tid < 64) ((float4*)inl)[tid] = ((const float4*)(in + row0 * 16))[tid];
        __syncthreads();

        float4 acc = make_float4(bl[j4], bl[j4 + 1], bl[j4 + 2], bl[j4 + 3]);
        const float* a = &inl[r * 16];
        #pragma unroll
        for (int k = 0; k < 16; k += 4) {
            const float4 a4 = *(const float4*)(a + k);
            float4 w;
            w = *(const float4*)(&Wl[(k + 0) * 64 + j4]);
            acc.x += a4.x * w.x; acc.y += a4.x * w.y; acc.z += a4.x * w.z; acc.w += a4.x * w.w;
            w = *(const float4*)(&Wl[(k + 1) * 64 + j4]);
            acc.x += a4.y * w.x; acc.y += a4.y * w.y; acc.z += a4.y * w.z; acc.w += a4.y * w.w;
            w = *(const float4*)(&Wl[(k + 2) * 64 + j4]);
            acc.x += a4.z * w.x; acc.y += a4.z * w.y; acc.z += a4.z * w.z; acc.w += a4.z * w.w;
            w = *(const float4*)(&Wl[(k + 3) * 64 + j4]);
            acc.x += a4.w * w.x; acc.y += a4.w * w.y; acc.z += a4.w * w.z; acc.w += a4.w * w.w;
        }
        ushort4 ob;
        ob.x = f2bf(fmaxf(acc.x, 0.f)); ob.y = f2bf(fmaxf(acc.y, 0.f));
        ob.z = f2bf(fmaxf(acc.z, 0.f)); ob.w = f2bf(fmaxf(acc.w, 0.f));
        *(ushort4*)(out + (row0 + r) * 128 + half * 64 + j4) = ob;
        __syncthreads();
    }
}

// ---------- weight prep: W[K][128] f32 -> transposed, XOR-swizzled hi/lo bf16 ----------
// slot 0 = We2 (K=128), 1..4 = W1[l], 5..8 = W2[l], 9 = Wn (K=64).
__global__ __launch_bounds__(BLK) void prep_w(
    const float* __restrict__ Wn, const float* __restrict__ We2,
    const float* __restrict__ W1, const float* __restrict__ W2,
    unsigned short* __restrict__ wp)
{
    const int slot = blockIdx.y;
    const int K = (slot == 9) ? 64 : 128;
    const float* Wsrc = (slot == 0) ? We2
                      : (slot <= 4) ? W1 + (size_t)(slot - 1) * 16384
                      : (slot <= 8) ? W2 + (size_t)(slot - 5) * 16384
                      : Wn;
    const int i = blockIdx.x * BLK + threadIdx.x;
    if (i >= K * 128) return;
    const int k = i >> 7, n = i & 127;
    const float f = Wsrc[k * 128 + n];
    const unsigned short hi = f2bf(f);
    const unsigned short lo = f2bf(f - bf2f(hi));
    const int idx = n * K + (k ^ ((n & 7) << 3));
    unsigned short* base = wp + (size_t)slot * 32768;
    base[idx] = hi;
    base[K * 128 + idx] = lo;
}

// ---------- MFMA GEMM: out = (relu?)(A[M,KDIM] @ W[KDIM,128] + bias) ----------
template <int KDIM, int A_BF16, int OUT_BF16>
__global__ __launch_bounds__(BLK) void gemm128(
    const void* __restrict__ Av, const unsigned short* __restrict__ Wp,
    const float* __restrict__ bias, void* __restrict__ outv,
    int M, int do_relu)
{
    __shared__ unsigned short Bl[2 * KDIM * 128];
    const int tid = threadIdx.x;
    {
        const float4* s = (const float4*)Wp;
        float4* d = (float4*)Bl;
        #pragma unroll
        for (int i = 0; i < KDIM / 8; ++i) d[tid + i * BLK] = s[tid + i * BLK];
    }
    __syncthreads();

    const int lane = tid & 63;
    const int wv   = tid >> 6;
    const int l15  = lane & 15;
    const int g    = lane >> 4;
    const int wbase = wv * 32;
    const int NKS = KDIM / 32;

    float bcol[8];
    #pragma unroll
    for (int cf = 0; cf < 8; ++cf) bcol[cf] = bias[cf * 16 + l15];

    const int ntiles = (M + 127) >> 7;
    for (int tile = blockIdx.x; tile < ntiles; tile += gridDim.x) {
        bf16x8 af[2][KDIM / 32];
        #pragma unroll
        for (int rf = 0; rf < 2; ++rf) {
            const int row = tile * 128 + wbase + rf * 16 + l15;
            const bool ok = row < M;
            #pragma unroll
            for (int ks = 0; ks < NKS; ++ks) {
                const int k0 = ks * 32 + g * 8;
                if (A_BF16) {
                    af[rf][ks] = ok
                        ? *(const bf16x8*)((const unsigned short*)Av + (size_t)row * KDIM + k0)
                        : (bf16x8)0;
                } else {
                    if (ok) {
                        const float* ap = (const float*)Av + (size_t)row * KDIM + k0;
                        const float4 f0 = *(const float4*)(ap);
                        const float4 f1 = *(const float4*)(ap + 4);
                        bf16x8 a;
                        a[0] = (short)f2bf(f0.x); a[1] = (short)f2bf(f0.y);
                        a[2] = (short)f2bf(f0.z); a[3] = (short)f2bf(f0.w);
                        a[4] = (short)f2bf(f1.x); a[5] = (short)f2bf(f1.y);
                        a[6] = (short)f2bf(f1.z); a[7] = (short)f2bf(f1.w);
                        af[rf][ks] = a;
                    } else af[rf][ks] = (bf16x8)0;
                }
            }
        }
        f32x4 acc[2][8];
        #pragma unroll
        for (int rf = 0; rf < 2; ++rf)
            #pragma unroll
            for (int cf = 0; cf < 8; ++cf) {
                const float b = bcol[cf];
                acc[rf][cf][0] = b; acc[rf][cf][1] = b;
                acc[rf][cf][2] = b; acc[rf][cf][3] = b;
            }
        #pragma unroll
        for (int ks = 0; ks < NKS; ++ks) {
            #pragma unroll
            for (int cf = 0; cf < 8; ++cf) {
                const int c = cf * 16 + l15;
                const int ku = (ks * 32 + g * 8) ^ ((c & 7) << 3);
                const bf16x8 bh = *(const bf16x8*)(&Bl[c * KDIM + ku]);
                const bf16x8 blo = *(const bf16x8*)(&Bl[KDIM * 128 + c * KDIM + ku]);
                acc[0][cf] = __builtin_amdgcn_mfma_f32_16x16x32_bf16(af[0][ks], bh, acc[0][cf], 0, 0, 0);
                acc[1][cf] = __builtin_amdgcn_mfma_f32_16x16x32_bf16(af[1][ks], bh, acc[1][cf], 0, 0, 0);
                acc[0][cf] = __builtin_amdgcn_mfma_f32_16x16x32_bf16(af[0][ks], blo, acc[0][cf], 0, 0, 0);
                acc[1][cf] = __builtin_amdgcn_mfma_f32_16x16x32_bf16(af[1][ks], blo, acc[1][cf], 0, 0, 0);
            }
        }
        #pragma unroll
        for (int rf = 0; rf < 2; ++rf) {
            const int r0 = tile * 128 + wbase + rf * 16 + g * 4;
            #pragma unroll
            for (int cf = 0; cf < 8; ++cf) {
                const int col = cf * 16 + l15;
                const f32x4 v = acc[rf][cf];
                #pragma unroll
                for (int j = 0; j < 4; ++j) {
                    const int row = r0 + j;
                    if (row < M) {
                        float x = v[j];
                        if (do_relu) x = fmaxf(x, 0.f);
                        if (OUT_BF16)
                            ((unsigned short*)outv)[(size_t)row * 128 + col] = f2bf(x);
                        else
                            ((float*)outv)[(size_t)row * 128 + col] = x;
                    }
                }
            }
        }
    }
}

// ---------- CSR build ----------
__global__ __launch_bounds__(BLK) void hist_k(
    const int* __restrict__ dst, int* __restrict__ counts, int nE)
{
    int i = blockIdx.x * BLK + threadIdx.x;
    if (i < nE) atomicAdd(&counts[dst[i]], 1);
}

__global__ __launch_bounds__(BLK) void scan1_k(
    const int* __restrict__ counts, int* __restrict__ blockSums, int n)
{
    __shared__ int s[BLK];
    const int t = threadIdx.x, b = blockIdx.x;
    const int base = b * 1024 + t * 4;
    int sum = 0;
    #pragma unroll
    for (int j = 0; j < 4; ++j) { int i = base + j; if (i < n) sum += counts[i]; }
    s[t] = sum; __syncthreads();
    for (int off = 128; off > 0; off >>= 1) {
        if (t < off) s[t] += s[t + off];
        __syncthreads();
    }
    if (t == 0) blockSums[b] = s[0];
}

__global__ void scan2_k(int* __restrict__ blockSums, int nb,
                        int* __restrict__ offsets, int n)
{
    if (threadIdx.x == 0 && blockIdx.x == 0) {
        int run = 0;
        for (int i = 0; i < nb; ++i) { int v = blockSums[i]; blockSums[i] = run; run += v; }
        offsets[n] = run;
    }
}

__global__ __launch_bounds__(BLK) void scan3_k(
    const int* __restrict__ counts, const int* __restrict__ blockSums,
    int* __restrict__ offsets, int n)
{
    __shared__ int s[BLK];
    const int t = threadIdx.x, b = blockIdx.x;
    const int base = b * 1024 + t * 4;
    int c[4]; int tsum = 0;
    #pragma unroll
    for (int j = 0; j < 4; ++j) {
        c[j] = (base + j < n) ? counts[base + j] : 0;
        tsum += c[j];
    }
    s[t] = tsum; __syncthreads();
    for (int off = 1; off < BLK; off <<= 1) {
        int v = (t >= off) ? s[t - off] : 0;
        __syncthreads();
        s[t] += v;
        __syncthreads();
    }
    int run = s[t] - tsum + blockSums[b];
    #pragma unroll
    for (int j = 0; j < 4; ++j) {
        if (base + j < n) { offsets[base + j] = run; run += c[j]; }
    }
}

__global__ __launch_bounds__(BLK) void fill_k(
    const int* __restrict__ dst, const int* __restrict__ offsets,
    int* __restrict__ cursor, int* __restrict__ eidx, int nE)
{
    int i = blockIdx.x * BLK + threadIdx.x;
    if (i < nE) {
        int d = dst[i];
        int pos = offsets[d] + atomicAdd(&cursor[d], 1);
        eidx[pos] = i;
    }
}

// permute edge inputs into CSR order
__global__ __launch_bounds__(BLK) void perm_k(
    const float* __restrict__ ef, const int* __restrict__ src,
    const int* __restrict__ eidx, float* __restrict__ ef_perm,
    int* __restrict__ src_perm, int nE)
{
    int i = blockIdx.x * BLK + threadIdx.x;
    if (i >= nE * 4) return;
    const int pos = i >> 2, part = i & 3;
    const int eg = eidx[pos];
    ((float4*)(ef_perm + (size_t)pos * 16))[part] =
        ((const float4*)(ef + (size_t)eg * 16))[part];
    if (part == 0) src_perm[pos] = src[eg];
}

// ---- aggregation: z[n] = h[n] + sum relu(h[sp[i]] + e[i]), all bf16 storage ----
// e/src_perm CSR-ordered (sequential); h gathers random (bf16 rows = 256B).
// Edge loop unrolled x4: independent load chains to hide gather latency.
__global__ __launch_bounds__(BLK) void agg_k(
    const unsigned short* __restrict__ h, const unsigned short* __restrict__ e,
    const int* __restrict__ src_perm, const int* __restrict__ offsets,
    unsigned short* __restrict__ z, int nN)
{
    const int t = threadIdx.x;
    const int node = blockIdx.x * 8 + (t >> 5);
    if (node >= nN) return;
    const int c4 = (t & 31) << 2;
    const ushort4 hn = *(const ushort4*)(h + (size_t)node * 128 + c4);
    float ax = bf2f(hn.x), ay = bf2f(hn.y), az = bf2f(hn.z), aw = bf2f(hn.w);
    const int beg = offsets[node], end = offsets[node + 1];
    int i = beg;
    for (; i + 4 <= end; i += 4) {
        const int s0 = src_perm[i], s1 = src_perm[i + 1];
        const int s2 = src_perm[i + 2], s3 = src_perm[i + 3];
        const ushort4 h0 = *(const ushort4*)(h + (size_t)s0 * 128 + c4);
        const ushort4 h1 = *(const ushort4*)(h + (size_t)s1 * 128 + c4);
        const ushort4 h2 = *(const ushort4*)(h + (size_t)s2 * 128 + c4);
        const ushort4 h3 = *(const ushort4*)(h + (size_t)s3 * 128 + c4);
        const ushort4 e0 = *(const ushort4*)(e + (size_t)(i + 0) * 128 + c4);
        const ushort4 e1 = *(const ushort4*)(e + (size_t)(i + 1) * 128 + c4);
        const ushort4 e2 = *(const ushort4*)(e + (size_t)(i + 2) * 128 + c4);
        const ushort4 e3 = *(const ushort4*)(e + (size_t)(i + 3) * 128 + c4);
        ax += fmaxf(bf2f(h0.x) + bf2f(e0.x), 0.f) + fmaxf(bf2f(h1.x) + bf2f(e1.x), 0.f)
            + fmaxf(bf2f(h2.x) + bf2f(e2.x), 0.f) + fmaxf(bf2f(h3.x) + bf2f(e3.x), 0.f);
        ay += fmaxf(bf2f(h0.y) + bf2f(e0.y), 0.f) + fmaxf(bf2f(h1.y) + bf2f(e1.y), 0.f)
            + fmaxf(bf2f(h2.y) + bf2f(e2.y), 0.f) + fmaxf(bf2f(h3.y) + bf2f(e3.y), 0.f);
        az += fmaxf(bf2f(h0.z) + bf2f(e0.z), 0.f) + fmaxf(bf2f(h1.z) + bf2f(e1.z), 0.f)
            + fmaxf(bf2f(h2.z) + bf2f(e2.z), 0.f) + fmaxf(bf2f(h3.z) + bf2f(e3.z), 0.f);
        aw += fmaxf(bf2f(h0.w) + bf2f(e0.w), 0.f) + fmaxf(bf2f(h1.w) + bf2f(e1.w), 0.f)
            + fmaxf(bf2f(h2.w) + bf2f(e2.w), 0.f) + fmaxf(bf2f(h3.w) + bf2f(e3.w), 0.f);
    }
    for (; i < end; ++i) {
        const int s = src_perm[i];
        const ushort4 hv = *(const ushort4*)(h + (size_t)s * 128 + c4);
        const ushort4 ev = *(const ushort4*)(e + (size_t)i * 128 + c4);
        ax += fmaxf(bf2f(hv.x) + bf2f(ev.x), 0.f);
        ay += fmaxf(bf2f(hv.y) + bf2f(ev.y), 0.f);
        az += fmaxf(bf2f(hv.z) + bf2f(ev.z), 0.f);
        aw += fmaxf(bf2f(hv.w) + bf2f(ev.w), 0.f);
    }
    ushort4 ob;
    ob.x = f2bf(ax); ob.y = f2bf(ay); ob.z = f2bf(az); ob.w = f2bf(aw);
    *(ushort4*)(z + (size_t)node * 128 + c4) = ob;
}

extern "C" void kernel_launch(void* const* d_in, const int* in_sizes, int n_in,
                              void* d_out, int out_size, void* d_ws, size_t ws_size,
                              hipStream_t stream) {
    const float* nf  = (const float*)d_in[0];
    const float* ef  = (const float*)d_in[1];
    const int*   src = (const int*)d_in[2];
    const int*   dst = (const int*)d_in[3];
    const float* Wn  = (const float*)d_in[4];
    const float* bn  = (const float*)d_in[5];
    const float* We1 = (const float*)d_in[6];
    const float* be1 = (const float*)d_in[7];
    const float* We2 = (const float*)d_in[8];
    const float* be2 = (const float*)d_in[9];
    const float* W1  = (const float*)d_in[10];
    const float* b1  = (const float*)d_in[11];
    const float* W2  = (const float*)d_in[12];
    const float* b2  = (const float*)d_in[13];

    const int N_ = 100000, E_ = 600000, L_ = 4;

    // workspace (~236.7 MB; known-safe budget 256 MB):
    //   e bf16 [E,128] (CSR order)  153.6 MB @ 0
    //   region R (76.8 MB) @ eB:
    //     layer phase: z bf16 25.6 @ R | hb bf16 25.6 @ R+25.6M | hidN bf16 25.6 @ R+51.2M
    //     edge  phase: ef_perm f32 38.4 @ R | hidE bf16 38.4 @ R+38.4M
    //     (init gemm runs AFTER edge phase: hb clobbers ef_perm tail safely)
    //   CSR @ csrOff: eidx|counts|offsets|blockSums|src_perm (~5.6 MB)
    //   wp @ wpOff: 10 x 64 KB
    const size_t eB = (size_t)E_ * 128 * 2;    // 153,600,000
    const size_t nb = (size_t)N_ * 128 * 2;    //  25,600,000
    const size_t csrOff = eB + 3 * nb;         // 230,400,000
    const size_t wpOff  = csrOff + 5601088;
    const size_t need = wpOff + 10 * 65536;
    if (ws_size < need) return;

    char* ws = (char*)d_ws;
    unsigned short* e    = (unsigned short*)ws;
    unsigned short* z    = (unsigned short*)(ws + eB);
    unsigned short* hb   = (unsigned short*)(ws + eB + nb);
    unsigned short* hidN = (unsigned short*)(ws + eB + 2 * nb);
    float*          ef_perm = (float*)(ws + eB);                    // edge-phase alias
    unsigned short* hidE = (unsigned short*)(ws + eB + 38400000);   // edge-phase alias
    int* eidx      = (int*)(ws + csrOff);
    int* counts    = (int*)(ws + csrOff + 2400000);
    int* offsets   = (int*)(ws + csrOff + 2800000);
    int* blockSums = (int*)(ws + csrOff + 3200064);
    int* src_perm  = (int*)(ws + csrOff + 3201088);
    unsigned short* wp = (unsigned short*)(ws + wpOff);

    dim3 blk(BLK);
    const int nbE = (E_ + BLK - 1) / BLK;
    const int nbScan = (N_ + 1023) / 1024;

    prep_w<<<dim3(64, 10), blk, 0, stream>>>(Wn, We2, W1, W2, wp);

    // CSR build (dst layer-invariant)
    hipMemsetAsync(counts, 0, (size_t)N_ * 4, stream);
    hist_k<<<nbE, blk, 0, stream>>>(dst, counts, E_);
    scan1_k<<<nbScan, blk, 0, stream>>>(counts, blockSums, N_);
    scan2_k<<<1, 64, 0, stream>>>(blockSums, nbScan, offsets, N_);
    scan3_k<<<nbScan, blk, 0, stream>>>(counts, blockSums, offsets, N_);
    hipMemsetAsync(counts, 0, (size_t)N_ * 4, stream);
    fill_k<<<nbE, blk, 0, stream>>>(dst, offsets, counts, eidx, E_);

    perm_k<<<(E_ * 4 + BLK - 1) / BLK, blk, 0, stream>>>(
        ef, src, eidx, ef_perm, src_perm, E_);

    // edge MLP: e = relu(ef_perm @ We1 + be1) @ We2 + be2 (CSR order), 4 chunks
    const int Mc = E_ / 4;  // 150000
    for (int c = 0; c < 4; ++c) {
        const float* efc = ef_perm + (size_t)c * Mc * 16;
        unsigned short* ec = e + (size_t)c * Mc * 128;
        gemm_rm16<<<dim3(2048, 2), blk, 0, stream>>>(efc, We1, be1, hidE, Mc);
        gemm128<128, 1, 1><<<dim3(1024), blk, 0, stream>>>(hidE, wp, be2, ec, Mc, 0);
    }

    // init: hb = relu(nf @ Wn + bn)  (after edge phase; clobbers ef_perm region)
    const int gxN = (N_ + 127) / 128;   // 782
    gemm128<64, 0, 1><<<dim3(gxN), blk, 0, stream>>>(
        nf, wp + (size_t)9 * 32768, bn, hb, N_, 1);

    // L GINE layers
    const int nbAgg = (N_ + 7) / 8;
    for (int l = 0; l < L_; ++l) {
        agg_k<<<nbAgg, blk, 0, stream>>>(hb, e, src_perm, offsets, z, N_);
        gemm128<128, 1, 1><<<dim3(gxN), blk, 0, stream>>>(
            z, wp + (size_t)(1 + l) * 32768, b1 + (size_t)l * 128, hidN, N_, 1);
        if (l < L_ - 1)
            gemm128<128, 1, 1><<<dim3(gxN), blk, 0, stream>>>(
                hidN, wp + (size_t)(5 + l) * 32768, b2 + (size_t)l * 128, hb, N_, 1);
        else
            gemm128<128, 1, 0><<<dim3(gxN), blk, 0, stream>>>(
                hidN, wp + (size_t)(5 + l) * 32768, b2 + (size_t)l * 128, d_out, N_, 1);
    }
}

// Round 9
// 746.856 us; speedup vs baseline: 7.9715x; 1.1939x over previous
//
#include <hip/hip_runtime.h>

#define BLK 256

typedef short bf16x8 __attribute__((ext_vector_type(8)));
typedef float f32x4 __attribute__((ext_vector_type(4)));

__device__ __forceinline__ unsigned short f2bf(float f) {
    unsigned int u = __float_as_uint(f);
    u += 0x7FFFu + ((u >> 16) & 1u);
    return (unsigned short)(u >> 16);
}
__device__ __forceinline__ float bf2f(unsigned short s) {
    return __uint_as_float(((unsigned int)s) << 16);
}

// ---------- weight prep ----------
// slot 0 = We2 (K=128), 1..4 = W1[l] (128), 5..8 = W2[l] (128), 9 = Wn (64),
// 10 = We1 zero-padded to K=32 (swizzle mask 3).
// Element (k,n) at ushort idx n*K + (k ^ ((n&mask)<<3)); hi at base, lo at +K*128.
__global__ __launch_bounds__(BLK) void prep_w(
    const float* __restrict__ Wn, const float* __restrict__ We1,
    const float* __restrict__ We2, const float* __restrict__ W1,
    const float* __restrict__ W2, unsigned short* __restrict__ wp)
{
    const int slot = blockIdx.y;
    const int K = (slot == 9) ? 64 : (slot == 10) ? 32 : 128;
    const int i = blockIdx.x * BLK + threadIdx.x;
    if (i >= K * 128) return;
    const int k = i >> 7, n = i & 127;
    float f;
    if (slot == 0)      f = We2[k * 128 + n];
    else if (slot <= 4) f = W1[(size_t)(slot - 1) * 16384 + k * 128 + n];
    else if (slot <= 8) f = W2[(size_t)(slot - 5) * 16384 + k * 128 + n];
    else if (slot == 9) f = Wn[k * 128 + n];
    else                f = (k < 16) ? We1[k * 128 + n] : 0.f;
    const unsigned short hi = f2bf(f);
    const unsigned short lo = f2bf(f - bf2f(hi));
    const int mask = (slot == 10) ? 3 : 7;
    const int idx = n * K + (k ^ ((n & mask) << 3));
    unsigned short* base = wp + (size_t)slot * 32768;
    base[idx] = hi;
    base[K * 128 + idx] = lo;
}

// ---------- MFMA GEMM: out = (relu?)(A[M,KDIM] @ W[KDIM,128] + bias) ----------
template <int KDIM, int A_BF16, int OUT_BF16>
__global__ __launch_bounds__(BLK) void gemm128(
    const void* __restrict__ Av, const unsigned short* __restrict__ Wp,
    const float* __restrict__ bias, void* __restrict__ outv,
    int M, int do_relu)
{
    __shared__ unsigned short Bl[2 * KDIM * 128];
    const int tid = threadIdx.x;
    {
        const float4* s = (const float4*)Wp;
        float4* d = (float4*)Bl;
        #pragma unroll
        for (int i = 0; i < KDIM / 8; ++i) d[tid + i * BLK] = s[tid + i * BLK];
    }
    __syncthreads();

    const int lane = tid & 63;
    const int wv   = tid >> 6;
    const int l15  = lane & 15;
    const int g    = lane >> 4;
    const int wbase = wv * 32;
    const int NKS = KDIM / 32;

    float bcol[8];
    #pragma unroll
    for (int cf = 0; cf < 8; ++cf) bcol[cf] = bias[cf * 16 + l15];

    const int ntiles = (M + 127) >> 7;
    for (int tile = blockIdx.x; tile < ntiles; tile += gridDim.x) {
        bf16x8 af[2][KDIM / 32];
        #pragma unroll
        for (int rf = 0; rf < 2; ++rf) {
            const int row = tile * 128 + wbase + rf * 16 + l15;
            const bool ok = row < M;
            #pragma unroll
            for (int ks = 0; ks < NKS; ++ks) {
                const int k0 = ks * 32 + g * 8;
                if (A_BF16) {
                    af[rf][ks] = ok
                        ? *(const bf16x8*)((const unsigned short*)Av + (size_t)row * KDIM + k0)
                        : (bf16x8)0;
                } else {
                    if (ok) {
                        const float* ap = (const float*)Av + (size_t)row * KDIM + k0;
                        const float4 f0 = *(const float4*)(ap);
                        const float4 f1 = *(const float4*)(ap + 4);
                        bf16x8 a;
                        a[0] = (short)f2bf(f0.x); a[1] = (short)f2bf(f0.y);
                        a[2] = (short)f2bf(f0.z); a[3] = (short)f2bf(f0.w);
                        a[4] = (short)f2bf(f1.x); a[5] = (short)f2bf(f1.y);
                        a[6] = (short)f2bf(f1.z); a[7] = (short)f2bf(f1.w);
                        af[rf][ks] = a;
                    } else af[rf][ks] = (bf16x8)0;
                }
            }
        }
        f32x4 acc[2][8];
        #pragma unroll
        for (int rf = 0; rf < 2; ++rf)
            #pragma unroll
            for (int cf = 0; cf < 8; ++cf) {
                const float b = bcol[cf];
                acc[rf][cf][0] = b; acc[rf][cf][1] = b;
                acc[rf][cf][2] = b; acc[rf][cf][3] = b;
            }
        #pragma unroll
        for (int ks = 0; ks < NKS; ++ks) {
            #pragma unroll
            for (int cf = 0; cf < 8; ++cf) {
                const int c = cf * 16 + l15;
                const int ku = (ks * 32 + g * 8) ^ ((c & 7) << 3);
                const bf16x8 bh = *(const bf16x8*)(&Bl[c * KDIM + ku]);
                const bf16x8 blo = *(const bf16x8*)(&Bl[KDIM * 128 + c * KDIM + ku]);
                acc[0][cf] = __builtin_amdgcn_mfma_f32_16x16x32_bf16(af[0][ks], bh, acc[0][cf], 0, 0, 0);
                acc[1][cf] = __builtin_amdgcn_mfma_f32_16x16x32_bf16(af[1][ks], bh, acc[1][cf], 0, 0, 0);
                acc[0][cf] = __builtin_amdgcn_mfma_f32_16x16x32_bf16(af[0][ks], blo, acc[0][cf], 0, 0, 0);
                acc[1][cf] = __builtin_amdgcn_mfma_f32_16x16x32_bf16(af[1][ks], blo, acc[1][cf], 0, 0, 0);
            }
        }
        #pragma unroll
        for (int rf = 0; rf < 2; ++rf) {
            const int r0 = tile * 128 + wbase + rf * 16 + g * 4;
            #pragma unroll
            for (int cf = 0; cf < 8; ++cf) {
                const int col = cf * 16 + l15;
                const f32x4 v = acc[rf][cf];
                #pragma unroll
                for (int j = 0; j < 4; ++j) {
                    const int row = r0 + j;
                    if (row < M) {
                        float x = v[j];
                        if (do_relu) x = fmaxf(x, 0.f);
                        if (OUT_BF16)
                            ((unsigned short*)outv)[(size_t)row * 128 + col] = f2bf(x);
                        else
                            ((float*)outv)[(size_t)row * 128 + col] = x;
                    }
                }
            }
        }
    }
}

// ---------- fused edge MLP: e = (relu(ef @ We1 + be1)) @ We2 + be2 ----------
// LDS: We1 hi/lo (K=32 padded, 16KB) + We2 hi-only (32KB) + per-wave swizzled
// bf16 stage 16x128 (16KB) = 64KB -> 2 blocks/CU.
__global__ __launch_bounds__(BLK) void edge_mlp(
    const float* __restrict__ ef, const unsigned short* __restrict__ w1p,
    const unsigned short* __restrict__ w2p, const float* __restrict__ be1,
    const float* __restrict__ be2, unsigned short* __restrict__ out, int M)
{
    __shared__ unsigned short B1[2 * 32 * 128];   // hi [0,4096), lo [4096,8192)
    __shared__ unsigned short B2[128 * 128];      // hi only
    __shared__ unsigned short stg[4][16 * 128];
    const int tid = threadIdx.x;
    {
        const float4* s1 = (const float4*)w1p;
        float4* d1 = (float4*)B1;
        #pragma unroll
        for (int i = 0; i < 4; ++i) d1[tid + i * BLK] = s1[tid + i * BLK];
        const float4* s2 = (const float4*)w2p;   // hi half occupies first 16384 ushorts
        float4* d2 = (float4*)B2;
        #pragma unroll
        for (int i = 0; i < 8; ++i) d2[tid + i * BLK] = s2[tid + i * BLK];
    }
    __syncthreads();

    const int lane = tid & 63;
    const int wv   = tid >> 6;
    const int l15  = lane & 15;
    const int g    = lane >> 4;
    const int wbase = wv * 32;

    float bcol1[8], bcol2[8];
    #pragma unroll
    for (int cf = 0; cf < 8; ++cf) {
        bcol1[cf] = be1[cf * 16 + l15];
        bcol2[cf] = be2[cf * 16 + l15];
    }

    const int ntiles = (M + 127) >> 7;
    for (int tile = blockIdx.x; tile < ntiles; tile += gridDim.x) {
        #pragma unroll
        for (int rf = 0; rf < 2; ++rf) {
            const int row = tile * 128 + wbase + rf * 16 + l15;
            const bool ok = row < M;
            // layer-1 A frag (K=32, upper 16 zero): row=l15, k=g*8..g*8+7
            bf16x8 a1 = (bf16x8)0;
            if (g < 2 && ok) {
                const float* ap = ef + (size_t)row * 16 + g * 8;
                const float4 f0 = *(const float4*)(ap);
                const float4 f1 = *(const float4*)(ap + 4);
                a1[0] = (short)f2bf(f0.x); a1[1] = (short)f2bf(f0.y);
                a1[2] = (short)f2bf(f0.z); a1[3] = (short)f2bf(f0.w);
                a1[4] = (short)f2bf(f1.x); a1[5] = (short)f2bf(f1.y);
                a1[6] = (short)f2bf(f1.z); a1[7] = (short)f2bf(f1.w);
            }
            f32x4 acc1[8];
            #pragma unroll
            for (int cf = 0; cf < 8; ++cf) {
                const float b = bcol1[cf];
                acc1[cf][0] = b; acc1[cf][1] = b; acc1[cf][2] = b; acc1[cf][3] = b;
            }
            #pragma unroll
            for (int cf = 0; cf < 8; ++cf) {
                const int c = cf * 16 + l15;
                const int ku = (g * 8) ^ ((c & 3) << 3);
                const bf16x8 bh  = *(const bf16x8*)(&B1[c * 32 + ku]);
                const bf16x8 blo = *(const bf16x8*)(&B1[4096 + c * 32 + ku]);
                acc1[cf] = __builtin_amdgcn_mfma_f32_16x16x32_bf16(a1, bh,  acc1[cf], 0, 0, 0);
                acc1[cf] = __builtin_amdgcn_mfma_f32_16x16x32_bf16(a1, blo, acc1[cf], 0, 0, 0);
            }
            // relu -> swizzled bf16 stage (wave-local 16x128)
            #pragma unroll
            for (int cf = 0; cf < 8; ++cf) {
                const int col = cf * 16 + l15;
                #pragma unroll
                for (int j = 0; j < 4; ++j) {
                    const int rl = g * 4 + j;
                    stg[wv][rl * 128 + (col ^ ((rl & 7) << 3))] =
                        f2bf(fmaxf(acc1[cf][j], 0.f));
                }
            }
            __syncthreads();
            // layer-2 A frags from stage: row=l15, k0=ks*32+g*8 (8 contiguous)
            bf16x8 a2[4];
            #pragma unroll
            for (int ks = 0; ks < 4; ++ks) {
                const int k0 = ks * 32 + g * 8;
                a2[ks] = *(const bf16x8*)(&stg[wv][l15 * 128 + (k0 ^ ((l15 & 7) << 3))]);
            }
            f32x4 acc2[8];
            #pragma unroll
            for (int cf = 0; cf < 8; ++cf) {
                const float b = bcol2[cf];
                acc2[cf][0] = b; acc2[cf][1] = b; acc2[cf][2] = b; acc2[cf][3] = b;
            }
            #pragma unroll
            for (int ks = 0; ks < 4; ++ks) {
                #pragma unroll
                for (int cf = 0; cf < 8; ++cf) {
                    const int c = cf * 16 + l15;
                    const int ku = (ks * 32 + g * 8) ^ ((c & 7) << 3);
                    const bf16x8 bh = *(const bf16x8*)(&B2[c * 128 + ku]);
                    acc2[cf] = __builtin_amdgcn_mfma_f32_16x16x32_bf16(a2[ks], bh, acc2[cf], 0, 0, 0);
                }
            }
            // epilogue (no relu), bf16 out
            const int r0 = tile * 128 + wbase + rf * 16 + g * 4;
            #pragma unroll
            for (int cf = 0; cf < 8; ++cf) {
                const int col = cf * 16 + l15;
                #pragma unroll
                for (int j = 0; j < 4; ++j) {
                    const int r = r0 + j;
                    if (r < M) out[(size_t)r * 128 + col] = f2bf(acc2[cf][j]);
                }
            }
            __syncthreads();
        }
    }
}

// ---------- CSR build ----------
__global__ __launch_bounds__(BLK) void hist_k(
    const int* __restrict__ dst, int* __restrict__ counts, int nE)
{
    int i = blockIdx.x * BLK + threadIdx.x;
    if (i < nE) atomicAdd(&counts[dst[i]], 1);
}

__global__ __launch_bounds__(BLK) void scan1_k(
    const int* __restrict__ counts, int* __restrict__ blockSums, int n)
{
    __shared__ int s[BLK];
    const int t = threadIdx.x, b = blockIdx.x;
    const int base = b * 1024 + t * 4;
    int sum = 0;
    #pragma unroll
    for (int j = 0; j < 4; ++j) { int i = base + j; if (i < n) sum += counts[i]; }
    s[t] = sum; __syncthreads();
    for (int off = 128; off > 0; off >>= 1) {
        if (t < off) s[t] += s[t + off];
        __syncthreads();
    }
    if (t == 0) blockSums[b] = s[0];
}

__global__ void scan2_k(int* __restrict__ blockSums, int nb,
                        int* __restrict__ offsets, int n)
{
    if (threadIdx.x == 0 && blockIdx.x == 0) {
        int run = 0;
        for (int i = 0; i < nb; ++i) { int v = blockSums[i]; blockSums[i] = run; run += v; }
        offsets[n] = run;
    }
}

__global__ __launch_bounds__(BLK) void scan3_k(
    const int* __restrict__ counts, const int* __restrict__ blockSums,
    int* __restrict__ offsets, int n)
{
    __shared__ int s[BLK];
    const int t = threadIdx.x, b = blockIdx.x;
    const int base = b * 1024 + t * 4;
    int c[4]; int tsum = 0;
    #pragma unroll
    for (int j = 0; j < 4; ++j) {
        c[j] = (base + j < n) ? counts[base + j] : 0;
        tsum += c[j];
    }
    s[t] = tsum; __syncthreads();
    for (int off = 1; off < BLK; off <<= 1) {
        int v = (t >= off) ? s[t - off] : 0;
        __syncthreads();
        s[t] += v;
        __syncthreads();
    }
    int run = s[t] - tsum + blockSums[b];
    #pragma unroll
    for (int j = 0; j < 4; ++j) {
        if (base + j < n) { offsets[base + j] = run; run += c[j]; }
    }
}

__global__ __launch_bounds__(BLK) void fill_k(
    const int* __restrict__ dst, const int* __restrict__ offsets,
    int* __restrict__ cursor, int* __restrict__ eidx, int nE)
{
    int i = blockIdx.x * BLK + threadIdx.x;
    if (i < nE) {
        int d = dst[i];
        int pos = offsets[d] + atomicAdd(&cursor[d], 1);
        eidx[pos] = i;
    }
}

// permute edge inputs into CSR order
__global__ __launch_bounds__(BLK) void perm_k(
    const float* __restrict__ ef, const int* __restrict__ src,
    const int* __restrict__ eidx, float* __restrict__ ef_perm,
    int* __restrict__ src_perm, int nE)
{
    int i = blockIdx.x * BLK + threadIdx.x;
    if (i >= nE * 4) return;
    const int pos = i >> 2, part = i & 3;
    const int eg = eidx[pos];
    ((float4*)(ef_perm + (size_t)pos * 16))[part] =
        ((const float4*)(ef + (size_t)eg * 16))[part];
    if (part == 0) src_perm[pos] = src[eg];
}

// ---- aggregation: z[n] = h[n] + sum relu(h[sp[i]] + e[i]); bf16 storage ----
// Masked unroll-8: no serial tail; 16 independent loads in flight per round.
__global__ __launch_bounds__(BLK) void agg_k(
    const unsigned short* __restrict__ h, const unsigned short* __restrict__ e,
    const int* __restrict__ src_perm, const int* __restrict__ offsets,
    unsigned short* __restrict__ z, int nN)
{
    const int t = threadIdx.x;
    const int node = blockIdx.x * 8 + (t >> 5);
    if (node >= nN) return;
    const int c4 = (t & 31) << 2;
    const ushort4 hn = *(const ushort4*)(h + (size_t)node * 128 + c4);
    float ax = bf2f(hn.x), ay = bf2f(hn.y), az = bf2f(hn.z), aw = bf2f(hn.w);
    const int beg = offsets[node], end = offsets[node + 1];
    const int lim = end - 1;
    for (int i = beg; i < end; i += 8) {
        #pragma unroll
        for (int k = 0; k < 8; ++k) {
            const int idx = i + k;
            const bool v = idx < end;
            const int ic = v ? idx : lim;
            const int s = src_perm[ic];
            const ushort4 hv = *(const ushort4*)(h + (size_t)s * 128 + c4);
            const ushort4 ev = *(const ushort4*)(e + (size_t)ic * 128 + c4);
            const float mx = fmaxf(bf2f(hv.x) + bf2f(ev.x), 0.f);
            const float my = fmaxf(bf2f(hv.y) + bf2f(ev.y), 0.f);
            const float mz = fmaxf(bf2f(hv.z) + bf2f(ev.z), 0.f);
            const float mw = fmaxf(bf2f(hv.w) + bf2f(ev.w), 0.f);
            ax += v ? mx : 0.f;
            ay += v ? my : 0.f;
            az += v ? mz : 0.f;
            aw += v ? mw : 0.f;
        }
    }
    ushort4 ob;
    ob.x = f2bf(ax); ob.y = f2bf(ay); ob.z = f2bf(az); ob.w = f2bf(aw);
    *(ushort4*)(z + (size_t)node * 128 + c4) = ob;
}

extern "C" void kernel_launch(void* const* d_in, const int* in_sizes, int n_in,
                              void* d_out, int out_size, void* d_ws, size_t ws_size,
                              hipStream_t stream) {
    const float* nf  = (const float*)d_in[0];
    const float* ef  = (const float*)d_in[1];
    const int*   src = (const int*)d_in[2];
    const int*   dst = (const int*)d_in[3];
    const float* Wn  = (const float*)d_in[4];
    const float* bn  = (const float*)d_in[5];
    const float* We1 = (const float*)d_in[6];
    const float* be1 = (const float*)d_in[7];
    const float* We2 = (const float*)d_in[8];
    const float* be2 = (const float*)d_in[9];
    const float* W1  = (const float*)d_in[10];
    const float* b1  = (const float*)d_in[11];
    const float* W2  = (const float*)d_in[12];
    const float* b2  = (const float*)d_in[13];

    const int N_ = 100000, E_ = 600000, L_ = 4;

    // workspace (~237 MB; known-safe budget 256 MB):
    //   e bf16 [E,128] (CSR order)  153.6 MB @ 0
    //   region R (76.8 MB) @ eB:
    //     layer phase: z bf16 @ R | hb bf16 @ R+25.6M | hidN bf16 @ R+51.2M
    //     edge  phase: ef_perm f32 [E,16] 38.4 MB @ R (dead before init gemm)
    //   CSR @ csrOff: eidx|counts|offsets|blockSums|src_perm (~5.6 MB)
    //   wp @ wpOff: 11 x 64 KB weight slots
    const size_t eB = (size_t)E_ * 128 * 2;    // 153,600,000
    const size_t nb = (size_t)N_ * 128 * 2;    //  25,600,000
    const size_t csrOff = eB + 3 * nb;         // 230,400,000
    const size_t wpOff  = csrOff + 5601088;
    const size_t need = wpOff + 11 * 65536;
    if (ws_size < need) return;

    char* ws = (char*)d_ws;
    unsigned short* e    = (unsigned short*)ws;
    unsigned short* z    = (unsigned short*)(ws + eB);
    unsigned short* hb   = (unsigned short*)(ws + eB + nb);
    unsigned short* hidN = (unsigned short*)(ws + eB + 2 * nb);
    float*          ef_perm = (float*)(ws + eB);    // edge-phase alias
    int* eidx      = (int*)(ws + csrOff);
    int* counts    = (int*)(ws + csrOff + 2400000);
    int* offsets   = (int*)(ws + csrOff + 2800000);
    int* blockSums = (int*)(ws + csrOff + 3200064);
    int* src_perm  = (int*)(ws + csrOff + 3201088);
    unsigned short* wp = (unsigned short*)(ws + wpOff);

    dim3 blk(BLK);
    const int nbE = (E_ + BLK - 1) / BLK;
    const int nbScan = (N_ + 1023) / 1024;

    prep_w<<<dim3(64, 11), blk, 0, stream>>>(Wn, We1, We2, W1, W2, wp);

    // CSR build (dst layer-invariant)
    hipMemsetAsync(counts, 0, (size_t)N_ * 4, stream);
    hist_k<<<nbE, blk, 0, stream>>>(dst, counts, E_);
    scan1_k<<<nbScan, blk, 0, stream>>>(counts, blockSums, N_);
    scan2_k<<<1, 64, 0, stream>>>(blockSums, nbScan, offsets, N_);
    scan3_k<<<nbScan, blk, 0, stream>>>(counts, blockSums, offsets, N_);
    hipMemsetAsync(counts, 0, (size_t)N_ * 4, stream);
    fill_k<<<nbE, blk, 0, stream>>>(dst, offsets, counts, eidx, E_);

    perm_k<<<(E_ * 4 + BLK - 1) / BLK, blk, 0, stream>>>(
        ef, src, eidx, ef_perm, src_perm, E_);

    // fused edge MLP: e = relu(ef_perm @ We1 + be1) @ We2 + be2  (CSR order)
    edge_mlp<<<dim3(2048), blk, 0, stream>>>(
        ef_perm, wp + (size_t)10 * 32768, wp, be1, be2, e, E_);

    // init: hb = relu(nf @ Wn + bn)
    const int gxN = (N_ + 127) / 128;   // 782
    gemm128<64, 0, 1><<<dim3(gxN), blk, 0, stream>>>(
        nf, wp + (size_t)9 * 32768, bn, hb, N_, 1);

    // L GINE layers
    const int nbAgg = (N_ + 7) / 8;
    for (int l = 0; l < L_; ++l) {
        agg_k<<<nbAgg, blk, 0, stream>>>(hb, e, src_perm, offsets, z, N_);
        gemm128<128, 1, 1><<<dim3(gxN), blk, 0, stream>>>(
            z, wp + (size_t)(1 + l) * 32768, b1 + (size_t)l * 128, hidN, N_, 1);
        if (l < L_ - 1)
            gemm128<128, 1, 1><<<dim3(gxN), blk, 0, stream>>>(
                hidN, wp + (size_t)(5 + l) * 32768, b2 + (size_t)l * 128, hb, N_, 1);
        else
            gemm128<128, 1, 0><<<dim3(gxN), blk, 0, stream>>>(
                hidN, wp + (size_t)(5 + l) * 32768, b2 + (size_t)l * 128, d_out, N_, 1);
    }
}

// Round 10
// 675.395 us; speedup vs baseline: 8.8149x; 1.1058x over previous
//
#include <hip/hip_runtime.h>

#define BLK 256

typedef short bf16x8 __attribute__((ext_vector_type(8)));
typedef float f32x4 __attribute__((ext_vector_type(4)));

__device__ __forceinline__ unsigned short f2bf(float f) {
    unsigned int u = __float_as_uint(f);
    u += 0x7FFFu + ((u >> 16) & 1u);
    return (unsigned short)(u >> 16);
}
__device__ __forceinline__ float bf2f(unsigned short s) {
    return __uint_as_float(((unsigned int)s) << 16);
}

// ---------- weight prep ----------
// slot 0 = We2 (K=128), 1..4 = W1[l] (128), 5..8 = W2[l] (128), 9 = Wn (64),
// 10 = We1 zero-padded to K=32 (swizzle mask 3).
// Element (k,n) at ushort idx n*K + (k ^ ((n&mask)<<3)); hi at base, lo at +K*128.
// Kernels with LO=0 read only the contiguous hi half.
__global__ __launch_bounds__(BLK) void prep_w(
    const float* __restrict__ Wn, const float* __restrict__ We1,
    const float* __restrict__ We2, const float* __restrict__ W1,
    const float* __restrict__ W2, unsigned short* __restrict__ wp)
{
    const int slot = blockIdx.y;
    const int K = (slot == 9) ? 64 : (slot == 10) ? 32 : 128;
    const int i = blockIdx.x * BLK + threadIdx.x;
    if (i >= K * 128) return;
    const int k = i >> 7, n = i & 127;
    float f;
    if (slot == 0)      f = We2[k * 128 + n];
    else if (slot <= 4) f = W1[(size_t)(slot - 1) * 16384 + k * 128 + n];
    else if (slot <= 8) f = W2[(size_t)(slot - 5) * 16384 + k * 128 + n];
    else if (slot == 9) f = Wn[k * 128 + n];
    else                f = (k < 16) ? We1[k * 128 + n] : 0.f;
    const unsigned short hi = f2bf(f);
    const unsigned short lo = f2bf(f - bf2f(hi));
    const int mask = (slot == 10) ? 3 : 7;
    const int idx = n * K + (k ^ ((n & mask) << 3));
    unsigned short* base = wp + (size_t)slot * 32768;
    base[idx] = hi;
    base[K * 128 + idx] = lo;
}

// ---------- MFMA GEMM: out = (relu?)(A[M,KDIM] @ W[KDIM,128] + bias) ----------
// LO=1 adds the weight lo-term (2x LDS, 2x MFMA) for extra precision.
template <int KDIM, int A_BF16, int OUT_BF16, int LO>
__global__ __launch_bounds__(BLK) void gemm128(
    const void* __restrict__ Av, const unsigned short* __restrict__ Wp,
    const float* __restrict__ bias, void* __restrict__ outv,
    int M, int do_relu)
{
    __shared__ unsigned short Bl[(LO ? 2 : 1) * KDIM * 128];
    const int tid = threadIdx.x;
    {
        const float4* s = (const float4*)Wp;
        float4* d = (float4*)Bl;
        #pragma unroll
        for (int i = 0; i < (LO ? KDIM / 8 : KDIM / 16); ++i)
            d[tid + i * BLK] = s[tid + i * BLK];
    }
    __syncthreads();

    const int lane = tid & 63;
    const int wv   = tid >> 6;
    const int l15  = lane & 15;
    const int g    = lane >> 4;
    const int wbase = wv * 32;
    const int NKS = KDIM / 32;

    float bcol[8];
    #pragma unroll
    for (int cf = 0; cf < 8; ++cf) bcol[cf] = bias[cf * 16 + l15];

    const int ntiles = (M + 127) >> 7;
    for (int tile = blockIdx.x; tile < ntiles; tile += gridDim.x) {
        bf16x8 af[2][KDIM / 32];
        #pragma unroll
        for (int rf = 0; rf < 2; ++rf) {
            const int row = tile * 128 + wbase + rf * 16 + l15;
            const bool ok = row < M;
            #pragma unroll
            for (int ks = 0; ks < NKS; ++ks) {
                const int k0 = ks * 32 + g * 8;
                if (A_BF16) {
                    af[rf][ks] = ok
                        ? *(const bf16x8*)((const unsigned short*)Av + (size_t)row * KDIM + k0)
                        : (bf16x8)0;
                } else {
                    if (ok) {
                        const float* ap = (const float*)Av + (size_t)row * KDIM + k0;
                        const float4 f0 = *(const float4*)(ap);
                        const float4 f1 = *(const float4*)(ap + 4);
                        bf16x8 a;
                        a[0] = (short)f2bf(f0.x); a[1] = (short)f2bf(f0.y);
                        a[2] = (short)f2bf(f0.z); a[3] = (short)f2bf(f0.w);
                        a[4] = (short)f2bf(f1.x); a[5] = (short)f2bf(f1.y);
                        a[6] = (short)f2bf(f1.z); a[7] = (short)f2bf(f1.w);
                        af[rf][ks] = a;
                    } else af[rf][ks] = (bf16x8)0;
                }
            }
        }
        f32x4 acc[2][8];
        #pragma unroll
        for (int rf = 0; rf < 2; ++rf)
            #pragma unroll
            for (int cf = 0; cf < 8; ++cf) {
                const float b = bcol[cf];
                acc[rf][cf][0] = b; acc[rf][cf][1] = b;
                acc[rf][cf][2] = b; acc[rf][cf][3] = b;
            }
        #pragma unroll
        for (int ks = 0; ks < NKS; ++ks) {
            #pragma unroll
            for (int cf = 0; cf < 8; ++cf) {
                const int c = cf * 16 + l15;
                const int ku = (ks * 32 + g * 8) ^ ((c & 7) << 3);
                const bf16x8 bh = *(const bf16x8*)(&Bl[c * KDIM + ku]);
                acc[0][cf] = __builtin_amdgcn_mfma_f32_16x16x32_bf16(af[0][ks], bh, acc[0][cf], 0, 0, 0);
                acc[1][cf] = __builtin_amdgcn_mfma_f32_16x16x32_bf16(af[1][ks], bh, acc[1][cf], 0, 0, 0);
                if (LO) {
                    const bf16x8 blo = *(const bf16x8*)(&Bl[KDIM * 128 + c * KDIM + ku]);
                    acc[0][cf] = __builtin_amdgcn_mfma_f32_16x16x32_bf16(af[0][ks], blo, acc[0][cf], 0, 0, 0);
                    acc[1][cf] = __builtin_amdgcn_mfma_f32_16x16x32_bf16(af[1][ks], blo, acc[1][cf], 0, 0, 0);
                }
            }
        }
        #pragma unroll
        for (int rf = 0; rf < 2; ++rf) {
            const int r0 = tile * 128 + wbase + rf * 16 + g * 4;
            #pragma unroll
            for (int cf = 0; cf < 8; ++cf) {
                const int col = cf * 16 + l15;
                const f32x4 v = acc[rf][cf];
                #pragma unroll
                for (int j = 0; j < 4; ++j) {
                    const int row = r0 + j;
                    if (row < M) {
                        float x = v[j];
                        if (do_relu) x = fmaxf(x, 0.f);
                        if (OUT_BF16)
                            ((unsigned short*)outv)[(size_t)row * 128 + col] = f2bf(x);
                        else
                            ((float*)outv)[(size_t)row * 128 + col] = x;
                    }
                }
            }
        }
    }
}

// ---------- fused edge MLP: e[pos] = relu(ef[eidx[pos]] @ We1 + be1) @ We2 + be2 ----------
// LDS: We1 hi (K=32 padded, 8KB) + We2 hi (32KB) + per-wave swizzled stage
// 16x128 bf16 (16KB) = 56KB. Stage is wave-private: no block barriers in loop.
__global__ __launch_bounds__(BLK) void edge_mlp(
    const float* __restrict__ ef, const int* __restrict__ eidx,
    const unsigned short* __restrict__ w1p, const unsigned short* __restrict__ w2p,
    const float* __restrict__ be1, const float* __restrict__ be2,
    unsigned short* __restrict__ out, int M)
{
    __shared__ unsigned short B1[32 * 128];       // hi only
    __shared__ unsigned short B2[128 * 128];      // hi only
    __shared__ unsigned short stg[4][16 * 128];
    const int tid = threadIdx.x;
    {
        const float4* s1 = (const float4*)w1p;
        float4* d1 = (float4*)B1;
        #pragma unroll
        for (int i = 0; i < 2; ++i) d1[tid + i * BLK] = s1[tid + i * BLK];
        const float4* s2 = (const float4*)w2p;
        float4* d2 = (float4*)B2;
        #pragma unroll
        for (int i = 0; i < 8; ++i) d2[tid + i * BLK] = s2[tid + i * BLK];
    }
    __syncthreads();

    const int lane = tid & 63;
    const int wv   = tid >> 6;
    const int l15  = lane & 15;
    const int g    = lane >> 4;
    const int wbase = wv * 32;

    float bcol1[8], bcol2[8];
    #pragma unroll
    for (int cf = 0; cf < 8; ++cf) {
        bcol1[cf] = be1[cf * 16 + l15];
        bcol2[cf] = be2[cf * 16 + l15];
    }

    const int ntiles = (M + 127) >> 7;
    for (int tile = blockIdx.x; tile < ntiles; tile += gridDim.x) {
        #pragma unroll
        for (int rf = 0; rf < 2; ++rf) {
            const int row = tile * 128 + wbase + rf * 16 + l15;
            const bool ok = row < M;
            // layer-1 A frag (K=32, upper 16 zero); gather source row via eidx
            bf16x8 a1 = (bf16x8)0;
            if (g < 2 && ok) {
                const int er = eidx[row];
                const float* ap = ef + (size_t)er * 16 + g * 8;
                const float4 f0 = *(const float4*)(ap);
                const float4 f1 = *(const float4*)(ap + 4);
                a1[0] = (short)f2bf(f0.x); a1[1] = (short)f2bf(f0.y);
                a1[2] = (short)f2bf(f0.z); a1[3] = (short)f2bf(f0.w);
                a1[4] = (short)f2bf(f1.x); a1[5] = (short)f2bf(f1.y);
                a1[6] = (short)f2bf(f1.z); a1[7] = (short)f2bf(f1.w);
            }
            f32x4 acc1[8];
            #pragma unroll
            for (int cf = 0; cf < 8; ++cf) {
                const float b = bcol1[cf];
                acc1[cf][0] = b; acc1[cf][1] = b; acc1[cf][2] = b; acc1[cf][3] = b;
            }
            #pragma unroll
            for (int cf = 0; cf < 8; ++cf) {
                const int c = cf * 16 + l15;
                const int ku = (g * 8) ^ ((c & 3) << 3);
                const bf16x8 bh = *(const bf16x8*)(&B1[c * 32 + ku]);
                acc1[cf] = __builtin_amdgcn_mfma_f32_16x16x32_bf16(a1, bh, acc1[cf], 0, 0, 0);
            }
            // relu -> swizzled bf16 stage (wave-private)
            #pragma unroll
            for (int cf = 0; cf < 8; ++cf) {
                const int col = cf * 16 + l15;
                #pragma unroll
                for (int j = 0; j < 4; ++j) {
                    const int rl = g * 4 + j;
                    stg[wv][rl * 128 + (col ^ ((rl & 7) << 3))] =
                        f2bf(fmaxf(acc1[cf][j], 0.f));
                }
            }
            // layer-2 A frags from stage (same-wave LDS dep; compiler orders)
            bf16x8 a2[4];
            #pragma unroll
            for (int ks = 0; ks < 4; ++ks) {
                const int k0 = ks * 32 + g * 8;
                a2[ks] = *(const bf16x8*)(&stg[wv][l15 * 128 + (k0 ^ ((l15 & 7) << 3))]);
            }
            f32x4 acc2[8];
            #pragma unroll
            for (int cf = 0; cf < 8; ++cf) {
                const float b = bcol2[cf];
                acc2[cf][0] = b; acc2[cf][1] = b; acc2[cf][2] = b; acc2[cf][3] = b;
            }
            #pragma unroll
            for (int ks = 0; ks < 4; ++ks) {
                #pragma unroll
                for (int cf = 0; cf < 8; ++cf) {
                    const int c = cf * 16 + l15;
                    const int ku = (ks * 32 + g * 8) ^ ((c & 7) << 3);
                    const bf16x8 bh = *(const bf16x8*)(&B2[c * 128 + ku]);
                    acc2[cf] = __builtin_amdgcn_mfma_f32_16x16x32_bf16(a2[ks], bh, acc2[cf], 0, 0, 0);
                }
            }
            // epilogue (no relu), bf16 out
            const int r0 = tile * 128 + wbase + rf * 16 + g * 4;
            #pragma unroll
            for (int cf = 0; cf < 8; ++cf) {
                const int col = cf * 16 + l15;
                #pragma unroll
                for (int j = 0; j < 4; ++j) {
                    const int r = r0 + j;
                    if (r < M) out[(size_t)r * 128 + col] = f2bf(acc2[cf][j]);
                }
            }
        }
    }
}

// ---------- CSR build ----------
__global__ __launch_bounds__(BLK) void hist_k(
    const int* __restrict__ dst, int* __restrict__ counts, int nE)
{
    int i = blockIdx.x * BLK + threadIdx.x;
    if (i < nE) atomicAdd(&counts[dst[i]], 1);
}

__global__ __launch_bounds__(BLK) void scan1_k(
    const int* __restrict__ counts, int* __restrict__ blockSums, int n)
{
    __shared__ int s[BLK];
    const int t = threadIdx.x, b = blockIdx.x;
    const int base = b * 1024 + t * 4;
    int sum = 0;
    #pragma unroll
    for (int j = 0; j < 4; ++j) { int i = base + j; if (i < n) sum += counts[i]; }
    s[t] = sum; __syncthreads();
    for (int off = 128; off > 0; off >>= 1) {
        if (t < off) s[t] += s[t + off];
        __syncthreads();
    }
    if (t == 0) blockSums[b] = s[0];
}

// parallel exclusive scan of block sums (nb <= 128), one 128-thread block
__global__ __launch_bounds__(128) void scan2_k(
    int* __restrict__ blockSums, int nb, int* __restrict__ offsets, int n)
{
    __shared__ int s[128];
    const int t = threadIdx.x;
    const int v = (t < nb) ? blockSums[t] : 0;
    s[t] = v; __syncthreads();
    for (int off = 1; off < 128; off <<= 1) {
        int u = (t >= off) ? s[t - off] : 0;
        __syncthreads();
        s[t] += u;
        __syncthreads();
    }
    if (t < nb) blockSums[t] = s[t] - v;
    if (t == 127) offsets[n] = s[127];
}

__global__ __launch_bounds__(BLK) void scan3_k(
    const int* __restrict__ counts, const int* __restrict__ blockSums,
    int* __restrict__ offsets, int n)
{
    __shared__ int s[BLK];
    const int t = threadIdx.x, b = blockIdx.x;
    const int base = b * 1024 + t * 4;
    int c[4]; int tsum = 0;
    #pragma unroll
    for (int j = 0; j < 4; ++j) {
        c[j] = (base + j < n) ? counts[base + j] : 0;
        tsum += c[j];
    }
    s[t] = tsum; __syncthreads();
    for (int off = 1; off < BLK; off <<= 1) {
        int v = (t >= off) ? s[t - off] : 0;
        __syncthreads();
        s[t] += v;
        __syncthreads();
    }
    int run = s[t] - tsum + blockSums[b];
    #pragma unroll
    for (int j = 0; j < 4; ++j) {
        if (base + j < n) { offsets[base + j] = run; run += c[j]; }
    }
}

// fill CSR edge list; also writes src_perm (CSR-ordered src) in the same pass
__global__ __launch_bounds__(BLK) void fill_k(
    const int* __restrict__ dst, const int* __restrict__ src,
    const int* __restrict__ offsets, int* __restrict__ cursor,
    int* __restrict__ eidx, int* __restrict__ src_perm, int nE)
{
    int i = blockIdx.x * BLK + threadIdx.x;
    if (i < nE) {
        int d = dst[i];
        int pos = offsets[d] + atomicAdd(&cursor[d], 1);
        eidx[pos] = i;
        src_perm[pos] = src[i];
    }
}

// ---- aggregation: z[n] = h[n] + sum relu(h[sp[i]] + e[i]); bf16 storage ----
// Masked unroll-8: no serial tail; 16 independent loads in flight per round.
__global__ __launch_bounds__(BLK) void agg_k(
    const unsigned short* __restrict__ h, const unsigned short* __restrict__ e,
    const int* __restrict__ src_perm, const int* __restrict__ offsets,
    unsigned short* __restrict__ z, int nN)
{
    const int t = threadIdx.x;
    const int node = blockIdx.x * 8 + (t >> 5);
    if (node >= nN) return;
    const int c4 = (t & 31) << 2;
    const ushort4 hn = *(const ushort4*)(h + (size_t)node * 128 + c4);
    float ax = bf2f(hn.x), ay = bf2f(hn.y), az = bf2f(hn.z), aw = bf2f(hn.w);
    const int beg = offsets[node], end = offsets[node + 1];
    const int lim = end - 1;
    for (int i = beg; i < end; i += 8) {
        #pragma unroll
        for (int k = 0; k < 8; ++k) {
            const int idx = i + k;
            const bool v = idx < end;
            const int ic = v ? idx : lim;
            const int s = src_perm[ic];
            const ushort4 hv = *(const ushort4*)(h + (size_t)s * 128 + c4);
            const ushort4 ev = *(const ushort4*)(e + (size_t)ic * 128 + c4);
            const float mx = fmaxf(bf2f(hv.x) + bf2f(ev.x), 0.f);
            const float my = fmaxf(bf2f(hv.y) + bf2f(ev.y), 0.f);
            const float mz = fmaxf(bf2f(hv.z) + bf2f(ev.z), 0.f);
            const float mw = fmaxf(bf2f(hv.w) + bf2f(ev.w), 0.f);
            ax += v ? mx : 0.f;
            ay += v ? my : 0.f;
            az += v ? mz : 0.f;
            aw += v ? mw : 0.f;
        }
    }
    ushort4 ob;
    ob.x = f2bf(ax); ob.y = f2bf(ay); ob.z = f2bf(az); ob.w = f2bf(aw);
    *(ushort4*)(z + (size_t)node * 128 + c4) = ob;
}

extern "C" void kernel_launch(void* const* d_in, const int* in_sizes, int n_in,
                              void* d_out, int out_size, void* d_ws, size_t ws_size,
                              hipStream_t stream) {
    const float* nf  = (const float*)d_in[0];
    const float* ef  = (const float*)d_in[1];
    const int*   src = (const int*)d_in[2];
    const int*   dst = (const int*)d_in[3];
    const float* Wn  = (const float*)d_in[4];
    const float* bn  = (const float*)d_in[5];
    const float* We1 = (const float*)d_in[6];
    const float* be1 = (const float*)d_in[7];
    const float* We2 = (const float*)d_in[8];
    const float* be2 = (const float*)d_in[9];
    const float* W1  = (const float*)d_in[10];
    const float* b1  = (const float*)d_in[11];
    const float* W2  = (const float*)d_in[12];
    const float* b2  = (const float*)d_in[13];

    const int N_ = 100000, E_ = 600000, L_ = 4;

    // workspace (~237 MB; known-safe budget 256 MB):
    //   e bf16 [E,128] (CSR order)  153.6 MB @ 0
    //   z bf16 @ eB | hb bf16 @ eB+nb | hidN bf16 @ eB+2nb   (3 x 25.6 MB)
    //   CSR @ csrOff: eidx|counts|offsets|blockSums|src_perm (~5.6 MB)
    //   wp @ wpOff: 11 x 64 KB weight slots (hi | lo halves)
    const size_t eB = (size_t)E_ * 128 * 2;    // 153,600,000
    const size_t nb = (size_t)N_ * 128 * 2;    //  25,600,000
    const size_t csrOff = eB + 3 * nb;         // 230,400,000
    const size_t wpOff  = csrOff + 5601088;
    const size_t need = wpOff + 11 * 65536;
    if (ws_size < need) return;

    char* ws = (char*)d_ws;
    unsigned short* e    = (unsigned short*)ws;
    unsigned short* z    = (unsigned short*)(ws + eB);
    unsigned short* hb   = (unsigned short*)(ws + eB + nb);
    unsigned short* hidN = (unsigned short*)(ws + eB + 2 * nb);
    int* eidx      = (int*)(ws + csrOff);
    int* counts    = (int*)(ws + csrOff + 2400000);
    int* offsets   = (int*)(ws + csrOff + 2800000);
    int* blockSums = (int*)(ws + csrOff + 3200064);
    int* src_perm  = (int*)(ws + csrOff + 3201088);
    unsigned short* wp = (unsigned short*)(ws + wpOff);

    dim3 blk(BLK);
    const int nbE = (E_ + BLK - 1) / BLK;
    const int nbScan = (N_ + 1023) / 1024;     // 98 <= 128

    prep_w<<<dim3(64, 11), blk, 0, stream>>>(Wn, We1, We2, W1, W2, wp);

    // CSR build (dst layer-invariant); fill also emits src_perm
    hipMemsetAsync(counts, 0, (size_t)N_ * 4, stream);
    hist_k<<<nbE, blk, 0, stream>>>(dst, counts, E_);
    scan1_k<<<nbScan, blk, 0, stream>>>(counts, blockSums, N_);
    scan2_k<<<1, 128, 0, stream>>>(blockSums, nbScan, offsets, N_);
    scan3_k<<<nbScan, blk, 0, stream>>>(counts, blockSums, offsets, N_);
    hipMemsetAsync(counts, 0, (size_t)N_ * 4, stream);
    fill_k<<<nbE, blk, 0, stream>>>(dst, src, offsets, counts, eidx, src_perm, E_);

    // fused edge MLP (gathers ef via eidx; writes e in CSR order)
    edge_mlp<<<dim3(2048), blk, 0, stream>>>(
        ef, eidx, wp + (size_t)10 * 32768, wp, be1, be2, e, E_);

    // init: hb = relu(nf @ Wn + bn)  (hi-only, 2 tiles/block)
    const int gx2 = ((N_ + 127) / 128 + 1) / 2;   // 391
    gemm128<64, 0, 1, 0><<<dim3(gx2), blk, 0, stream>>>(
        nf, wp + (size_t)9 * 32768, bn, hb, N_, 1);

    // L GINE layers
    const int nbAgg = (N_ + 7) / 8;
    for (int l = 0; l < L_; ++l) {
        agg_k<<<nbAgg, blk, 0, stream>>>(hb, e, src_perm, offsets, z, N_);
        gemm128<128, 1, 1, 0><<<dim3(gx2), blk, 0, stream>>>(
            z, wp + (size_t)(1 + l) * 32768, b1 + (size_t)l * 128, hidN, N_, 1);
        if (l < L_ - 1)
            gemm128<128, 1, 1, 0><<<dim3(gx2), blk, 0, stream>>>(
                hidN, wp + (size_t)(5 + l) * 32768, b2 + (size_t)l * 128, hb, N_, 1);
        else  // final layer keeps hi+lo precision into f32 output
            gemm128<128, 1, 0, 1><<<dim3(gx2), blk, 0, stream>>>(
                hidN, wp + (size_t)(5 + l) * 32768, b2 + (size_t)l * 128, d_out, N_, 1);
    }
}